// Round 1
// baseline (1270.482 us; speedup 1.0000x reference)
//
#include <hip/hip_runtime.h>

// MemoAI fused block for MI355X (gfx950).
// Strategy:
//  - fp16x2 split-precision MFMA (hi + 2^11-scaled lo, 3 mfma per logical mac)
//    for everything upstream of MoE routing (routing needs ~fp32-exact x,
//    else top-2 expert flips blow past the 0.1 absmax threshold).
//  - plain fp16 MFMA for the expert FFN (post-routing, smooth error).
//  - sum(softmax(top2)) == 1, so moe weight multiplier is exactly 1.
//  - only the chosen expert is computed (tokens bucketed by expert).

typedef _Float16 f16;
typedef _Float16 f16x8 __attribute__((ext_vector_type(8)));
typedef float f32x4 __attribute__((ext_vector_type(4)));

constexpr int CS  = 1024;  // seq len
constexpr int CD  = 1024;  // model dim
constexpr int CH  = 16;    // heads
constexpr int CHD = 64;    // head dim
constexpr int CF  = 2048;  // ffn dim
constexpr int CE  = 8;     // experts
constexpr int CN  = 2048;  // tokens = B*S
constexpr int CBH = 32;    // B*H

constexpr float LO_SCALE = 2048.f;       // 2^11: keeps lo-parts normal in fp16
constexpr float LO_INV   = 1.f / 2048.f;

#define MFMA16(a, b, c) __builtin_amdgcn_mfma_f32_16x16x32_f16((a), (b), (c), 0, 0, 0)

__device__ __forceinline__ void fsplit(float v, f16 &hi, f16 &lo) {
  hi = (f16)v;
  lo = (f16)((v - (float)hi) * LO_SCALE);
}

// ---------------------------------------------------------------- conversions

__global__ void k_split_cvt(const float* __restrict__ in, f16* __restrict__ oh,
                            f16* __restrict__ ol, int n) {
  int i = (blockIdx.x * blockDim.x + threadIdx.x) * 4;
  if (i >= n) return;
  float4 v = *(const float4*)(in + i);
  float a[4] = {v.x, v.y, v.z, v.w};
#pragma unroll
  for (int j = 0; j < 4; ++j) {
    f16 hi = (f16)a[j];
    oh[i + j] = hi;
    ol[i + j] = (f16)((a[j] - (float)hi) * LO_SCALE);
  }
}

// in: [Z][R][C] f32 -> outH(/outL scaled) : [Z][C][R] f16
__global__ void k_transpose_split(const float* __restrict__ in, f16* __restrict__ oh,
                                  f16* __restrict__ ol, int R, int C) {
  __shared__ float t[32][33];
  const int z = blockIdx.z;
  const float* src = in + (size_t)z * R * C;
  f16* dh = oh + (size_t)z * R * C;
  f16* dl = ol ? ol + (size_t)z * R * C : nullptr;
  const int c0 = blockIdx.x * 32, r0 = blockIdx.y * 32;
  const int tx = threadIdx.x, ty = threadIdx.y;
#pragma unroll
  for (int i = 0; i < 32; i += 8)
    t[ty + i][tx] = src[(size_t)(r0 + ty + i) * C + c0 + tx];
  __syncthreads();
#pragma unroll
  for (int i = 0; i < 32; i += 8) {
    float v = t[tx][ty + i];
    f16 hi = (f16)v;
    size_t idx = (size_t)(c0 + ty + i) * R + r0 + tx;
    dh[idx] = hi;
    if (dl) dl[idx] = (f16)((v - (float)hi) * LO_SCALE);
  }
}

// ---------------------------------------------------------------- GEMM cores
// Wave computes 16 rows x 64 cols (4 subtiles of 16x16), K-major fp16 inputs.
// A fragment: lane reads A[m = lane&15][k0 + quad*8 .. +8]
// B fragment: lane reads Bt[n = lane&15][k0 + quad*8 .. +8]  (Bt = B^T)
// C/D: col = lane&15, row = quad*4 + reg   [verified layout, guide §3]

__device__ __forceinline__ void gemm_split(const f16* __restrict__ Ah, const f16* __restrict__ Al,
                                           const f16* __restrict__ Bh, const f16* __restrict__ Bl,
                                           int ldb, int K, int quad,
                                           f32x4 accm[4], f32x4 accc[4]) {
  for (int k = quad * 8; k < K; k += 32) {
    f16x8 ah = *(const f16x8*)(Ah + k);
    f16x8 al = *(const f16x8*)(Al + k);
#pragma unroll
    for (int t = 0; t < 4; ++t) {
      f16x8 bh = *(const f16x8*)(Bh + (size_t)t * 16 * ldb + k);
      f16x8 bl = *(const f16x8*)(Bl + (size_t)t * 16 * ldb + k);
      accm[t] = MFMA16(ah, bh, accm[t]);
      accc[t] = MFMA16(ah, bl, accc[t]);
      accc[t] = MFMA16(al, bh, accc[t]);
    }
  }
}

__device__ __forceinline__ void gemm_f16(const f16* __restrict__ A, const f16* __restrict__ B,
                                         int ldb, int K, int quad, f32x4 acc[4]) {
  for (int k = quad * 8; k < K; k += 32) {
    f16x8 a = *(const f16x8*)(A + k);
#pragma unroll
    for (int t = 0; t < 4; ++t) {
      f16x8 b = *(const f16x8*)(B + (size_t)t * 16 * ldb + k);
      acc[t] = MFMA16(a, b, acc[t]);
    }
  }
}

// ---------------------------------------------------------------- QKV

__global__ __launch_bounds__(256) void k_qkv(
    const f16* __restrict__ srcH, const f16* __restrict__ srcL,
    const f16* __restrict__ qwH, const f16* __restrict__ qwL,
    const f16* __restrict__ kwH, const f16* __restrict__ kwL,
    const f16* __restrict__ vwH, const f16* __restrict__ vwL,
    f16* __restrict__ qHo, f16* __restrict__ qLo,
    f16* __restrict__ kHo, f16* __restrict__ kLo,
    f16* __restrict__ vTH, f16* __restrict__ vTL) {
  const int lane = threadIdx.x & 63, wave = threadIdx.x >> 6;
  const int m = lane & 15, quad = lane >> 4;
  const int m0 = blockIdx.x * 16;
  const int n0 = blockIdx.y * 256 + wave * 64;
  const int z = blockIdx.z;
  const f16* BHp = (z == 0) ? qwH : (z == 1) ? kwH : vwH;
  const f16* BLp = (z == 0) ? qwL : (z == 1) ? kwL : vwL;
  const f32x4 VZ = {0.f, 0.f, 0.f, 0.f};
  f32x4 accm[4], accc[4];
#pragma unroll
  for (int t = 0; t < 4; ++t) { accm[t] = VZ; accc[t] = VZ; }
  gemm_split(srcH + (size_t)(m0 + m) * CD, srcL + (size_t)(m0 + m) * CD,
             BHp + (size_t)(n0 + m) * CD, BLp + (size_t)(n0 + m) * CD,
             CD, CD, quad, accm, accc);
#pragma unroll
  for (int t = 0; t < 4; ++t) {
#pragma unroll
    for (int r = 0; r < 4; ++r) {
      const int row = m0 + quad * 4 + r;   // token
      const int col = n0 + t * 16 + m;     // d
      const float v = accm[t][r] + accc[t][r] * LO_INV;
      f16 hi, lo; fsplit(v, hi, lo);
      const int bb = row >> 10, ss = row & 1023;
      const int hh = col >> 6, hd = col & 63;
      if (z == 2) {  // v stored transposed: [b,h,hd,s]
        const size_t idx = ((size_t)((bb * CH + hh) * CHD + hd)) * CS + ss;
        vTH[idx] = hi; vTL[idx] = lo;
      } else if (z == 0) {
        const size_t idx = ((size_t)((bb * CH + hh) * CS + ss)) * CHD + hd;
        qHo[idx] = hi; qLo[idx] = lo;
      } else {
        const size_t idx = ((size_t)((bb * CH + hh) * CS + ss)) * CHD + hd;
        kHo[idx] = hi; kLo[idx] = lo;
      }
    }
  }
}

// ------------------------------------------------------------ dynamic scale

__global__ void k_qscale(const f16* __restrict__ qH_, const f16* __restrict__ qL_,
                         const float* __restrict__ scale_w, float* __restrict__ qsc) {
  const int idx = blockIdx.x * blockDim.x + threadIdx.x;  // [0, BH*S)
  if (idx >= CBH * CS) return;
  const int bh = idx >> 10;
  const int h = bh & (CH - 1);
  const f16* ph = qH_ + (size_t)idx * CHD;
  const f16* pl = qL_ + (size_t)idx * CHD;
  const float* sw = scale_w + h * CHD;
  float s = 0.f;
#pragma unroll 8
  for (int j = 0; j < CHD; ++j)
    s += ((float)ph[j] + (float)pl[j] * LO_INV) * sw[j];
  qsc[idx] = 2.f / (1.f + __expf(-s));
}

// ---------------------------------------------------------------- attention
// One workgroup per (16 q-rows, b, h). Scores tile (16x1024 fp32, 64 KiB LDS,
// XOR-swizzled at 16B granule by (row&7) so PV A-frag reads are <=2-way).

__device__ __forceinline__ int swz(int row, int col) {
  return row * 1024 + (((col >> 2) ^ (row & 7)) << 2) + (col & 3);
}

__global__ __launch_bounds__(256) void k_attn(
    const f16* __restrict__ qH_, const f16* __restrict__ qL_,
    const f16* __restrict__ kH_, const f16* __restrict__ kL_,
    const f16* __restrict__ vTH_, const f16* __restrict__ vTL_,
    const float* __restrict__ qsc,
    f16* __restrict__ aoH, f16* __restrict__ aoL) {
  __shared__ float sc[16 * 1024];  // exactly 64 KiB
  const int bh = blockIdx.y;
  const int b = bh >> 4, h = bh & 15;
  const int q0 = blockIdx.x * 16;
  const int lane = threadIdx.x & 63, wave = threadIdx.x >> 6;
  const int m = lane & 15, quad = lane >> 4;
  const f32x4 VZ = {0.f, 0.f, 0.f, 0.f};

  // --- QK^T ---
  const f16* qrh = qH_ + ((size_t)(bh * CS) + q0 + m) * CHD + quad * 8;
  const f16* qrl = qL_ + ((size_t)(bh * CS) + q0 + m) * CHD + quad * 8;
  f16x8 a0h = *(const f16x8*)(qrh);
  f16x8 a1h = *(const f16x8*)(qrh + 32);
  f16x8 a0l = *(const f16x8*)(qrl);
  f16x8 a1l = *(const f16x8*)(qrl + 32);
  float qs[4];
#pragma unroll
  for (int r = 0; r < 4; ++r) qs[r] = qsc[bh * CS + q0 + quad * 4 + r] * 0.125f;
  for (int kt = wave; kt < 64; kt += 4) {
    const f16* krh = kH_ + ((size_t)(bh * CS) + kt * 16 + m) * CHD + quad * 8;
    const f16* krl = kL_ + ((size_t)(bh * CS) + kt * 16 + m) * CHD + quad * 8;
    f16x8 b0h = *(const f16x8*)(krh);
    f16x8 b1h = *(const f16x8*)(krh + 32);
    f16x8 b0l = *(const f16x8*)(krl);
    f16x8 b1l = *(const f16x8*)(krl + 32);
    f32x4 am = VZ, ac = VZ;
    am = MFMA16(a0h, b0h, am); ac = MFMA16(a0h, b0l, ac); ac = MFMA16(a0l, b0h, ac);
    am = MFMA16(a1h, b1h, am); ac = MFMA16(a1h, b1l, ac); ac = MFMA16(a1l, b1h, ac);
#pragma unroll
    for (int r = 0; r < 4; ++r)
      sc[swz(quad * 4 + r, kt * 16 + m)] = (am[r] + ac[r] * LO_INV) * qs[r];
  }
  __syncthreads();

  // --- softmax (16 threads per row) ---
  {
    const int row = threadIdx.x >> 4, sub = threadIdx.x & 15;
    float mx = -1e30f;
    for (int jj = 0; jj < 64; ++jj) mx = fmaxf(mx, sc[swz(row, sub + jj * 16)]);
#pragma unroll
    for (int msk = 8; msk >= 1; msk >>= 1) mx = fmaxf(mx, __shfl_xor(mx, msk));
    float sum = 0.f;
    for (int jj = 0; jj < 64; ++jj) {
      const int a = swz(row, sub + jj * 16);
      const float e = __expf(sc[a] - mx);
      sc[a] = e; sum += e;
    }
#pragma unroll
    for (int msk = 8; msk >= 1; msk >>= 1) sum += __shfl_xor(sum, msk);
    const float inv = 1.f / sum;
    for (int jj = 0; jj < 64; ++jj) sc[swz(row, sub + jj * 16)] *= inv;
  }
  __syncthreads();

  // --- P @ V (each wave: one 16-col slice of head dim) ---
  const f16* vrh = vTH_ + ((size_t)(bh * CHD) + wave * 16 + m) * CS + quad * 8;
  const f16* vrl = vTL_ + ((size_t)(bh * CHD) + wave * 16 + m) * CS + quad * 8;
  f32x4 accm = VZ, accc = VZ;
  for (int kb = 0; kb < 32; ++kb) {
    const int col0 = kb * 32 + quad * 8;
    float4 p0 = *(const float4*)(sc + swz(m, col0));
    float4 p1 = *(const float4*)(sc + swz(m, col0 + 4));
    float pv[8] = {p0.x, p0.y, p0.z, p0.w, p1.x, p1.y, p1.z, p1.w};
    f16x8 ah, al;
#pragma unroll
    for (int j = 0; j < 8; ++j) {
      f16 hi = (f16)pv[j];
      ah[j] = hi;
      al[j] = (f16)((pv[j] - (float)hi) * LO_SCALE);
    }
    f16x8 bh = *(const f16x8*)(vrh + kb * 32);
    f16x8 bl = *(const f16x8*)(vrl + kb * 32);
    accm = MFMA16(ah, bh, accm);
    accc = MFMA16(ah, bl, accc);
    accc = MFMA16(al, bh, accc);
  }
#pragma unroll
  for (int r = 0; r < 4; ++r) {
    const int srow = q0 + quad * 4 + r;
    const float v = accm[r] + accc[r] * LO_INV;
    f16 hi, lo; fsplit(v, hi, lo);
    const size_t idx = ((size_t)(b * CS + srow)) * CD + h * CHD + wave * 16 + m;
    aoH[idx] = hi; aoL[idx] = lo;
  }
}

// --------------------------------------------------------------- gate / out

__global__ __launch_bounds__(256) void k_gate(
    const f16* __restrict__ aoH, const f16* __restrict__ aoL,
    const f16* __restrict__ gwH, const f16* __restrict__ gwL,
    const float* __restrict__ gate_b,
    f16* __restrict__ gdH, f16* __restrict__ gdL) {
  const int lane = threadIdx.x & 63, wave = threadIdx.x >> 6;
  const int m = lane & 15, quad = lane >> 4;
  const int m0 = blockIdx.x * 16;
  const int n0 = blockIdx.y * 256 + wave * 64;
  const f32x4 VZ = {0.f, 0.f, 0.f, 0.f};
  f32x4 accm[4], accc[4];
#pragma unroll
  for (int t = 0; t < 4; ++t) { accm[t] = VZ; accc[t] = VZ; }
  gemm_split(aoH + (size_t)(m0 + m) * CD, aoL + (size_t)(m0 + m) * CD,
             gwH + (size_t)(n0 + m) * CD, gwL + (size_t)(n0 + m) * CD,
             CD, CD, quad, accm, accc);
#pragma unroll
  for (int t = 0; t < 4; ++t) {
#pragma unroll
    for (int r = 0; r < 4; ++r) {
      const int row = m0 + quad * 4 + r;
      const int col = n0 + t * 16 + m;
      const float pre = accm[t][r] + accc[t][r] * LO_INV + gate_b[col];
      const float g = 1.f / (1.f + __expf(-pre));
      const size_t idx = (size_t)row * CD + col;
      const float ov = (float)aoH[idx] + (float)aoL[idx] * LO_INV;
      f16 hi, lo; fsplit(ov * g, hi, lo);
      gdH[idx] = hi; gdL[idx] = lo;
    }
  }
}

__global__ __launch_bounds__(256) void k_outp(
    const f16* __restrict__ gdH, const f16* __restrict__ gdL,
    const f16* __restrict__ owH, const f16* __restrict__ owL,
    const float* __restrict__ src, float* __restrict__ y1) {
  const int lane = threadIdx.x & 63, wave = threadIdx.x >> 6;
  const int m = lane & 15, quad = lane >> 4;
  const int m0 = blockIdx.x * 16;
  const int n0 = blockIdx.y * 256 + wave * 64;
  const f32x4 VZ = {0.f, 0.f, 0.f, 0.f};
  f32x4 accm[4], accc[4];
#pragma unroll
  for (int t = 0; t < 4; ++t) { accm[t] = VZ; accc[t] = VZ; }
  gemm_split(gdH + (size_t)(m0 + m) * CD, gdL + (size_t)(m0 + m) * CD,
             owH + (size_t)(n0 + m) * CD, owL + (size_t)(n0 + m) * CD,
             CD, CD, quad, accm, accc);
#pragma unroll
  for (int t = 0; t < 4; ++t) {
#pragma unroll
    for (int r = 0; r < 4; ++r) {
      const int row = m0 + quad * 4 + r;
      const int col = n0 + t * 16 + m;
      const size_t idx = (size_t)row * CD + col;
      y1[idx] = src[idx] + accm[t][r] + accc[t][r] * LO_INV;
    }
  }
}

// -------------------------------------------------------------- layernorms

__device__ __forceinline__ void block_reduce2(float &s, float &ss, float* red) {
#pragma unroll
  for (int msk = 32; msk >= 1; msk >>= 1) {
    s += __shfl_xor(s, msk);
    ss += __shfl_xor(ss, msk);
  }
  const int wave = threadIdx.x >> 6, lane = threadIdx.x & 63;
  if (lane == 0) { red[wave] = s; red[4 + wave] = ss; }
  __syncthreads();
  s = red[0] + red[1] + red[2] + red[3];
  ss = red[4] + red[5] + red[6] + red[7];
}

__global__ __launch_bounds__(256) void k_ln1(
    const float* __restrict__ y1, const float* __restrict__ g, const float* __restrict__ bb,
    float* __restrict__ x, f16* __restrict__ xH) {
  __shared__ float red[8];
  const int n = blockIdx.x;
  const float* row = y1 + (size_t)n * CD;
  const int t = threadIdx.x;
  float4 v = *(const float4*)(row + t * 4);
  float a[4] = {v.x, v.y, v.z, v.w};
  float s = a[0] + a[1] + a[2] + a[3];
  float ss = a[0]*a[0] + a[1]*a[1] + a[2]*a[2] + a[3]*a[3];
  block_reduce2(s, ss, red);
  const float mean = s * (1.f / CD);
  const float var = ss * (1.f / CD) - mean * mean;
  const float rstd = rsqrtf(var + 1e-5f);
#pragma unroll
  for (int j = 0; j < 4; ++j) {
    const int d = t * 4 + j;
    const float val = (a[j] - mean) * rstd * g[d] + bb[d];
    x[(size_t)n * CD + d] = val;
    xH[(size_t)n * CD + d] = (f16)val;
  }
}

__global__ __launch_bounds__(256) void k_ln2(
    const float* __restrict__ z, const float* __restrict__ g, const float* __restrict__ bb,
    float* __restrict__ outp) {
  __shared__ float red[8];
  const int n = blockIdx.x;
  const float* row = z + (size_t)n * CD;
  const int t = threadIdx.x;
  float4 v = *(const float4*)(row + t * 4);
  float a[4] = {v.x, v.y, v.z, v.w};
  float s = a[0] + a[1] + a[2] + a[3];
  float ss = a[0]*a[0] + a[1]*a[1] + a[2]*a[2] + a[3]*a[3];
  block_reduce2(s, ss, red);
  const float mean = s * (1.f / CD);
  const float var = ss * (1.f / CD) - mean * mean;
  const float rstd = rsqrtf(var + 1e-5f);
#pragma unroll
  for (int j = 0; j < 4; ++j) {
    const int d = t * 4 + j;
    outp[(size_t)n * CD + d] = (a[j] - mean) * rstd * g[d] + bb[d];
  }
}

// ------------------------------------------------------------------ routing

__global__ void k_zero_counts(int* counts) {
  if (threadIdx.x < CE) counts[threadIdx.x] = 0;
}

__global__ __launch_bounds__(256) void k_route(
    const float* __restrict__ x, const float* __restrict__ gw, const float* __restrict__ gb,
    int* __restrict__ chosen, int* __restrict__ counts, int* __restrict__ bucket) {
  const int wave = threadIdx.x >> 6, lane = threadIdx.x & 63;
  const int n = blockIdx.x * 4 + wave;
  const float* xr = x + (size_t)n * CD;
  float acc[CE];
#pragma unroll
  for (int e = 0; e < CE; ++e) acc[e] = 0.f;
  for (int j = 0; j < 16; ++j) {
    const int d = lane * 16 + j;
    const float xv = xr[d];
    const float* wr = gw + (size_t)d * CE;
#pragma unroll
    for (int e = 0; e < CE; ++e) acc[e] += xv * wr[e];
  }
#pragma unroll
  for (int msk = 32; msk >= 1; msk >>= 1) {
#pragma unroll
    for (int e = 0; e < CE; ++e) acc[e] += __shfl_xor(acc[e], msk);
  }
  if (lane == 0) {
    float best = -1e30f, second = -1e30f;
    int bi = 0, si = 0;
#pragma unroll
    for (int e = 0; e < CE; ++e) {
      const float L = acc[e] + gb[e];
      if (L > best) { second = best; si = bi; best = L; bi = e; }
      else if (L > second) { second = L; si = e; }
    }
    const int ch = bi > si ? bi : si;  // torch-loop semantics: max index wins
    chosen[n] = ch;
    const int pos = atomicAdd(&counts[ch], 1);
    bucket[ch * CN + pos] = n;
  }
}

// ------------------------------------------------------------------ MoE FFN

__global__ __launch_bounds__(256) void k_moe1(
    const f16* __restrict__ xH, const f16* __restrict__ w1t,
    const float* __restrict__ b1, const int* __restrict__ counts,
    const int* __restrict__ bucket, float* __restrict__ hb) {
  const int e = blockIdx.z;
  const int cnt = counts[e];
  const int m0 = blockIdx.x * 16;
  if (m0 >= cnt) return;
  const int lane = threadIdx.x & 63, wave = threadIdx.x >> 6;
  const int m = lane & 15, quad = lane >> 4;
  const int n0 = blockIdx.y * 256 + wave * 64;
  const int* bk = bucket + e * CN;
  int ra = m0 + m; if (ra > cnt - 1) ra = cnt - 1;
  const int tokA = bk[ra];
  const f32x4 VZ = {0.f, 0.f, 0.f, 0.f};
  f32x4 acc[4];
#pragma unroll
  for (int t = 0; t < 4; ++t) acc[t] = VZ;
  gemm_f16(xH + (size_t)tokA * CD, w1t + ((size_t)e * CF + n0 + m) * CD, CD, CD, quad, acc);
  int tok[4];
#pragma unroll
  for (int r = 0; r < 4; ++r) {
    const int rr = m0 + quad * 4 + r;
    tok[r] = (rr < cnt) ? bk[rr] : -1;
  }
#pragma unroll
  for (int t = 0; t < 4; ++t) {
#pragma unroll
    for (int r = 0; r < 4; ++r) {
      if (tok[r] < 0) continue;
      const int col = n0 + t * 16 + m;
      hb[(size_t)tok[r] * CF + col] = acc[t][r] + b1[e * CF + col];
    }
  }
}

__global__ __launch_bounds__(256) void k_lngelu(
    const float* __restrict__ hb, const int* __restrict__ chosen,
    const float* __restrict__ ln_g, const float* __restrict__ ln_b,
    f16* __restrict__ h2) {
  __shared__ float red[8];
  const int n = blockIdx.x;
  const int e = chosen[n];
  const float* row = hb + (size_t)n * CF;
  const int t = threadIdx.x;
  float4 v0 = *(const float4*)(row + t * 8);
  float4 v1 = *(const float4*)(row + t * 8 + 4);
  float a[8] = {v0.x, v0.y, v0.z, v0.w, v1.x, v1.y, v1.z, v1.w};
  float s = 0.f, ss = 0.f;
#pragma unroll
  for (int j = 0; j < 8; ++j) { s += a[j]; ss += a[j] * a[j]; }
  block_reduce2(s, ss, red);
  const float mean = s * (1.f / CF);
  const float var = ss * (1.f / CF) - mean * mean;
  const float rstd = rsqrtf(var + 1e-5f);
  const float* g = ln_g + (size_t)e * CF;
  const float* bb = ln_b + (size_t)e * CF;
#pragma unroll
  for (int j = 0; j < 8; ++j) {
    const int d = t * 8 + j;
    const float val = (a[j] - mean) * rstd * g[d] + bb[d];
    const float gl = 0.5f * val * (1.f + erff(val * 0.70710678118654752f));
    h2[(size_t)n * CF + d] = (f16)gl;
  }
}

__global__ __launch_bounds__(256) void k_moe2(
    const f16* __restrict__ h2, const f16* __restrict__ w2t,
    const float* __restrict__ b2, const float* __restrict__ rsc,
    const int* __restrict__ counts, const int* __restrict__ bucket,
    const float* __restrict__ x, float* __restrict__ z) {
  const int e = blockIdx.z;
  const int cnt = counts[e];
  const int m0 = blockIdx.x * 16;
  if (m0 >= cnt) return;
  const int lane = threadIdx.x & 63, wave = threadIdx.x >> 6;
  const int m = lane & 15, quad = lane >> 4;
  const int n0 = blockIdx.y * 256 + wave * 64;
  const int* bk = bucket + e * CN;
  int ra = m0 + m; if (ra > cnt - 1) ra = cnt - 1;
  const int tokA = bk[ra];
  const f32x4 VZ = {0.f, 0.f, 0.f, 0.f};
  f32x4 acc[4];
#pragma unroll
  for (int t = 0; t < 4; ++t) acc[t] = VZ;
  gemm_f16(h2 + (size_t)tokA * CF, w2t + ((size_t)e * CD + n0 + m) * CF, CF, CF, quad, acc);
  const float rs = rsc[e];
  int tok[4];
#pragma unroll
  for (int r = 0; r < 4; ++r) {
    const int rr = m0 + quad * 4 + r;
    tok[r] = (rr < cnt) ? bk[rr] : -1;
  }
#pragma unroll
  for (int t = 0; t < 4; ++t) {
#pragma unroll
    for (int r = 0; r < 4; ++r) {
      if (tok[r] < 0) continue;
      const int col = n0 + t * 16 + m;
      const size_t idx = (size_t)tok[r] * CD + col;
      // z = x + moe ; moe = (h2@W2 + b2)*rsc + x   (top-2 weight sum == 1)
      z[idx] = 2.f * x[idx] + (acc[t][r] + b2[e * CD + col]) * rs;
    }
  }
}

// ------------------------------------------------------------------- launch

extern "C" void kernel_launch(void* const* d_in, const int* in_sizes, int n_in,
                              void* d_out, int out_size, void* d_ws, size_t ws_size,
                              hipStream_t stream) {
  (void)in_sizes; (void)n_in; (void)out_size; (void)ws_size;
  const float* src        = (const float*)d_in[0];
  const float* q_w        = (const float*)d_in[1];
  const float* k_w        = (const float*)d_in[2];
  const float* v_w        = (const float*)d_in[3];
  const float* out_w      = (const float*)d_in[4];
  const float* gate_w     = (const float*)d_in[5];
  const float* gate_b     = (const float*)d_in[6];
  const float* scale_w    = (const float*)d_in[7];
  const float* n1_g       = (const float*)d_in[8];
  const float* n1_b       = (const float*)d_in[9];
  const float* n2_g       = (const float*)d_in[10];
  const float* n2_b       = (const float*)d_in[11];
  const float* moe_gate_w = (const float*)d_in[12];
  const float* moe_gate_b = (const float*)d_in[13];
  const float* w1         = (const float*)d_in[14];
  const float* b1         = (const float*)d_in[15];
  const float* ln_g       = (const float*)d_in[16];
  const float* ln_b       = (const float*)d_in[17];
  const float* w2         = (const float*)d_in[18];
  const float* b2         = (const float*)d_in[19];
  const float* res_scale  = (const float*)d_in[20];
  float* outp = (float*)d_out;

  char* p = (char*)d_ws;
  auto take = [&](size_t bytes) -> char* {
    char* r = p;
    p += (bytes + 255) & ~(size_t)255;
    return r;
  };
  f16* srcH = (f16*)take((size_t)CN * CD * 2);
  f16* srcL = (f16*)take((size_t)CN * CD * 2);
  f16* qwH = (f16*)take((size_t)CD * CD * 2);
  f16* qwL = (f16*)take((size_t)CD * CD * 2);
  f16* kwH = (f16*)take((size_t)CD * CD * 2);
  f16* kwL = (f16*)take((size_t)CD * CD * 2);
  f16* vwH = (f16*)take((size_t)CD * CD * 2);
  f16* vwL = (f16*)take((size_t)CD * CD * 2);
  f16* gwH = (f16*)take((size_t)CD * CD * 2);
  f16* gwL = (f16*)take((size_t)CD * CD * 2);
  f16* owH = (f16*)take((size_t)CD * CD * 2);
  f16* owL = (f16*)take((size_t)CD * CD * 2);
  f16* qH = (f16*)take((size_t)CBH * CS * CHD * 2);
  f16* qL = (f16*)take((size_t)CBH * CS * CHD * 2);
  f16* kH = (f16*)take((size_t)CBH * CS * CHD * 2);
  f16* kL = (f16*)take((size_t)CBH * CS * CHD * 2);
  f16* vTH = (f16*)take((size_t)CBH * CS * CHD * 2);
  f16* vTL = (f16*)take((size_t)CBH * CS * CHD * 2);
  float* qsc = (float*)take((size_t)CBH * CS * 4);
  f16* aoH = (f16*)take((size_t)CN * CD * 2);
  f16* aoL = (f16*)take((size_t)CN * CD * 2);
  f16* gdH = (f16*)take((size_t)CN * CD * 2);
  f16* gdL = (f16*)take((size_t)CN * CD * 2);
  float* y1 = (float*)take((size_t)CN * CD * 4);
  float* x  = (float*)take((size_t)CN * CD * 4);
  f16* xH = (f16*)take((size_t)CN * CD * 2);
  int* counts = (int*)take(64);
  int* bucket = (int*)take((size_t)CE * CN * 4);
  int* chosen = (int*)take((size_t)CN * 4);
  float* hb = (float*)take((size_t)CN * CF * 4);
  f16* h2 = (f16*)take((size_t)CN * CF * 2);
  f16* w1t = (f16*)take((size_t)CE * CF * CD * 2);
  f16* w2t = (f16*)take((size_t)CE * CD * CF * 2);
  float* zb = (float*)take((size_t)CN * CD * 4);

  // --- input conversion / weight transposition ---
  k_split_cvt<<<dim3(CN * CD / 4 / 256), 256, 0, stream>>>(src, srcH, srcL, CN * CD);
  dim3 tb(32, 8);
  k_transpose_split<<<dim3(CD / 32, CD / 32, 1), tb, 0, stream>>>(q_w, qwH, qwL, CD, CD);
  k_transpose_split<<<dim3(CD / 32, CD / 32, 1), tb, 0, stream>>>(k_w, kwH, kwL, CD, CD);
  k_transpose_split<<<dim3(CD / 32, CD / 32, 1), tb, 0, stream>>>(v_w, vwH, vwL, CD, CD);
  k_transpose_split<<<dim3(CD / 32, CD / 32, 1), tb, 0, stream>>>(gate_w, gwH, gwL, CD, CD);
  k_transpose_split<<<dim3(CD / 32, CD / 32, 1), tb, 0, stream>>>(out_w, owH, owL, CD, CD);
  k_transpose_split<<<dim3(CF / 32, CD / 32, CE), tb, 0, stream>>>(w1, w1t, nullptr, CD, CF);
  k_transpose_split<<<dim3(CD / 32, CF / 32, CE), tb, 0, stream>>>(w2, w2t, nullptr, CF, CD);

  // --- attention ---
  k_qkv<<<dim3(CN / 16, CD / 256, 3), 256, 0, stream>>>(
      srcH, srcL, qwH, qwL, kwH, kwL, vwH, vwL, qH, qL, kH, kL, vTH, vTL);
  k_qscale<<<dim3(CBH * CS / 256), 256, 0, stream>>>(qH, qL, scale_w, qsc);
  k_attn<<<dim3(CS / 16, CBH), 256, 0, stream>>>(qH, qL, kH, kL, vTH, vTL, qsc, aoH, aoL);
  k_gate<<<dim3(CN / 16, CD / 256), 256, 0, stream>>>(aoH, aoL, gwH, gwL, gate_b, gdH, gdL);
  k_outp<<<dim3(CN / 16, CD / 256), 256, 0, stream>>>(gdH, gdL, owH, owL, src, y1);
  k_ln1<<<dim3(CN), 256, 0, stream>>>(y1, n1_g, n1_b, x, xH);

  // --- routing + MoE ---
  k_zero_counts<<<dim3(1), 64, 0, stream>>>(counts);
  k_route<<<dim3(CN / 4), 256, 0, stream>>>(x, moe_gate_w, moe_gate_b, chosen, counts, bucket);
  k_moe1<<<dim3(CN / 16, CF / 256, CE), 256, 0, stream>>>(xH, w1t, b1, counts, bucket, hb);
  k_lngelu<<<dim3(CN), 256, 0, stream>>>(hb, chosen, ln_g, ln_b, h2);
  k_moe2<<<dim3(CN / 16, CD / 256, CE), 256, 0, stream>>>(h2, w2t, b2, res_scale, counts, bucket, x, zb);
  k_ln2<<<dim3(CN), 256, 0, stream>>>(zb, n2_g, n2_b, outp);
}

// Round 2
// 795.980 us; speedup vs baseline: 1.5961x; 1.5961x over previous
//
#include <hip/hip_runtime.h>

// MemoAI fused block for MI355X (gfx950).
//  - fp16x2 split-precision MFMA (hi + 2^11-scaled lo) upstream of MoE routing
//  - plain fp16 MFMA for the expert FFN (post-routing)
//  - sum(softmax(top2)) == 1 -> moe weight multiplier is exactly 1
//  - only the chosen expert is computed (tokens bucketed by expert)
//  - R1: all GEMMs use a 64x128 LDS-staged core (global_load_lds width=16,
//    XOR-swizzled LDS so ds_read_b128 fragments are 2-way conflict = free)

typedef _Float16 f16;
typedef _Float16 f16x8 __attribute__((ext_vector_type(8)));
typedef float f32x4 __attribute__((ext_vector_type(4)));

constexpr int CS  = 1024;  // seq len
constexpr int CD  = 1024;  // model dim
constexpr int CH  = 16;    // heads
constexpr int CHD = 64;    // head dim
constexpr int CF  = 2048;  // ffn dim
constexpr int CE  = 8;     // experts
constexpr int CN  = 2048;  // tokens = B*S
constexpr int CBH = 32;    // B*H

constexpr float LO_SCALE = 2048.f;       // 2^11: keeps lo-parts normal in fp16
constexpr float LO_INV   = 1.f / 2048.f;

#define MFMA16(a, b, c) __builtin_amdgcn_mfma_f32_16x16x32_f16((a), (b), (c), 0, 0, 0)

#define TO_GBL(p) ((const __attribute__((address_space(1))) void*)(p))
#define TO_LDS(p) ((__attribute__((address_space(3))) void*)(p))
#define GLD16(g, l) __builtin_amdgcn_global_load_lds(TO_GBL(g), TO_LDS(l), 16, 0, 0)

__device__ __forceinline__ void fsplit(float v, f16 &hi, f16 &lo) {
  hi = (f16)v;
  lo = (f16)((v - (float)hi) * LO_SCALE);
}

// ---------------------------------------------------------------- conversions

__global__ void k_split_cvt(const float* __restrict__ in, f16* __restrict__ oh,
                            f16* __restrict__ ol, int n) {
  int i = (blockIdx.x * blockDim.x + threadIdx.x) * 4;
  if (i >= n) return;
  float4 v = *(const float4*)(in + i);
  float a[4] = {v.x, v.y, v.z, v.w};
#pragma unroll
  for (int j = 0; j < 4; ++j) {
    f16 hi = (f16)a[j];
    oh[i + j] = hi;
    ol[i + j] = (f16)((a[j] - (float)hi) * LO_SCALE);
  }
}

// in: [Z][R][C] f32 -> outH(/outL scaled) : [Z][C][R] f16
__global__ void k_transpose_split(const float* __restrict__ in, f16* __restrict__ oh,
                                  f16* __restrict__ ol, int R, int C) {
  __shared__ float t[32][33];
  const int z = blockIdx.z;
  const float* src = in + (size_t)z * R * C;
  f16* dh = oh + (size_t)z * R * C;
  f16* dl = ol ? ol + (size_t)z * R * C : nullptr;
  const int c0 = blockIdx.x * 32, r0 = blockIdx.y * 32;
  const int tx = threadIdx.x, ty = threadIdx.y;
#pragma unroll
  for (int i = 0; i < 32; i += 8)
    t[ty + i][tx] = src[(size_t)(r0 + ty + i) * C + c0 + tx];
  __syncthreads();
#pragma unroll
  for (int i = 0; i < 32; i += 8) {
    float v = t[tx][ty + i];
    f16 hi = (f16)v;
    size_t idx = (size_t)(c0 + ty + i) * R + r0 + tx;
    dh[idx] = hi;
    if (dl) dl[idx] = (f16)((v - (float)hi) * LO_SCALE);
  }
}

// ------------------------------------------------------------- tiled GEMM core
// Block tile 64(M) x 128(N), BK=32, 4 waves (2x2), wave tile 32x64.
// A [M x K] row-major (k-contig), B^T [N x K] row-major (k-contig), f16.
// LDS staged via global_load_lds (16 B/lane); layout swizzled: the 8-half
// k-chunk kc of row r is stored at chunk kc ^ ((r>>1)&3)  -> fragment
// ds_read_b128 is 2-way bank-aliased (free).
// Per-thread staging sources must be precomputed:
//   rowS = t>>2, ksw = ((t&3) ^ ((rowS>>1)&3))*8
//   aSrc = A_tile_base + rowS*lda + ksw   (advance +32/iter)
//   bSrc = B_tile_base + rowS*ldb + ksw   (+ second issue at +64*ldb)

template <bool SPLIT>
__device__ __forceinline__ void gemm_tile(
    const f16* aH, const f16* aL, const f16* bH, const f16* bL,
    size_t bRowStride /* 64*ldb */, int K, f16* lds,
    f32x4 (&accm)[2][4], f32x4 (&accc)[2][4]) {
  f16* lAh = lds;                          // 64*32  = 2048 halves
  f16* lAl = lds + 2048;                   // (split only)
  f16* lBh = lds + (SPLIT ? 4096 : 2048);  // 128*32 = 4096 halves
  f16* lBl = lds + 8192;                   // (split only)
  const int t = threadIdx.x;
  const int lane = t & 63, wave = t >> 6;
  const int wm = wave >> 1, wn = wave & 1;
  const int m16 = lane & 15, quad = lane >> 4;
  int aoff[2], boff[4];
#pragma unroll
  for (int sm = 0; sm < 2; ++sm) {
    const int r = wm * 32 + sm * 16 + m16;
    aoff[sm] = r * 32 + ((quad ^ ((r >> 1) & 3)) * 8);
  }
#pragma unroll
  for (int sn = 0; sn < 4; ++sn) {
    const int r = wn * 64 + sn * 16 + m16;
    boff[sn] = r * 32 + ((quad ^ ((r >> 1) & 3)) * 8);
  }
  for (int k = 0; k < K; k += 32) {
    GLD16(aH, lAh + t * 8);
    GLD16(bH, lBh + t * 8);
    GLD16(bH + bRowStride, lBh + 2048 + t * 8);
    if constexpr (SPLIT) {
      GLD16(aL, lAl + t * 8);
      GLD16(bL, lBl + t * 8);
      GLD16(bL + bRowStride, lBl + 2048 + t * 8);
      aL += 32; bL += 32;
    }
    aH += 32; bH += 32;
    __syncthreads();  // drains vmcnt(0) -> staged data visible
    f16x8 af[2], alf[2], bf[4], blf[4];
#pragma unroll
    for (int sm = 0; sm < 2; ++sm) {
      af[sm] = *(const f16x8*)(lAh + aoff[sm]);
      if constexpr (SPLIT) alf[sm] = *(const f16x8*)(lAl + aoff[sm]);
    }
#pragma unroll
    for (int sn = 0; sn < 4; ++sn) {
      bf[sn] = *(const f16x8*)(lBh + boff[sn]);
      if constexpr (SPLIT) blf[sn] = *(const f16x8*)(lBl + boff[sn]);
    }
#pragma unroll
    for (int sm = 0; sm < 2; ++sm)
#pragma unroll
      for (int sn = 0; sn < 4; ++sn) {
        accm[sm][sn] = MFMA16(af[sm], bf[sn], accm[sm][sn]);
        if constexpr (SPLIT) {
          accc[sm][sn] = MFMA16(af[sm], blf[sn], accc[sm][sn]);
          accc[sm][sn] = MFMA16(alf[sm], bf[sn], accc[sm][sn]);
        }
      }
    __syncthreads();  // all waves done reading before next overwrite
  }
}

// ---------------------------------------------------------------- QKV

__global__ __launch_bounds__(256) void g_qkv(
    const f16* __restrict__ srcH, const f16* __restrict__ srcL,
    const f16* __restrict__ qwH, const f16* __restrict__ qwL,
    const f16* __restrict__ kwH, const f16* __restrict__ kwL,
    const f16* __restrict__ vwH, const f16* __restrict__ vwL,
    f16* __restrict__ qHo, f16* __restrict__ qLo,
    f16* __restrict__ kHo, f16* __restrict__ kLo,
    f16* __restrict__ vTH, f16* __restrict__ vTL) {
  __shared__ f16 lds[12288];
  const int z = blockIdx.z;
  const int m0 = blockIdx.x * 64, n0 = blockIdx.y * 128;
  const int t = threadIdx.x;
  const int rowS = t >> 2;
  const int ksw = ((t & 3) ^ ((rowS >> 1) & 3)) * 8;
  const f16* BH = (z == 0) ? qwH : (z == 1) ? kwH : vwH;
  const f16* BL = (z == 0) ? qwL : (z == 1) ? kwL : vwL;
  const f32x4 VZ = {0.f, 0.f, 0.f, 0.f};
  f32x4 accm[2][4], accc[2][4];
#pragma unroll
  for (int i = 0; i < 2; ++i)
#pragma unroll
    for (int j = 0; j < 4; ++j) { accm[i][j] = VZ; accc[i][j] = VZ; }
  gemm_tile<true>(srcH + (size_t)(m0 + rowS) * CD + ksw,
                  srcL + (size_t)(m0 + rowS) * CD + ksw,
                  BH + (size_t)(n0 + rowS) * CD + ksw,
                  BL + (size_t)(n0 + rowS) * CD + ksw,
                  (size_t)64 * CD, CD, lds, accm, accc);
  const int lane = t & 63, wave = t >> 6;
  const int wm = wave >> 1, wn = wave & 1;
  const int m16 = lane & 15, quad = lane >> 4;
#pragma unroll
  for (int sm = 0; sm < 2; ++sm)
#pragma unroll
    for (int sn = 0; sn < 4; ++sn)
#pragma unroll
      for (int r = 0; r < 4; ++r) {
        const int row = m0 + wm * 32 + sm * 16 + quad * 4 + r;  // token
        const int col = n0 + wn * 64 + sn * 16 + m16;           // d
        const float v = accm[sm][sn][r] + accc[sm][sn][r] * LO_INV;
        f16 hi, lo; fsplit(v, hi, lo);
        const int bb = row >> 10, ss = row & 1023;
        const int hh = col >> 6, hd = col & 63;
        if (z == 2) {  // v stored transposed: [b,h,hd,s]
          const size_t idx = ((size_t)((bb * CH + hh) * CHD + hd)) * CS + ss;
          vTH[idx] = hi; vTL[idx] = lo;
        } else {
          const size_t idx = ((size_t)((bb * CH + hh) * CS + ss)) * CHD + hd;
          if (z == 0) { qHo[idx] = hi; qLo[idx] = lo; }
          else        { kHo[idx] = hi; kLo[idx] = lo; }
        }
      }
}

// ------------------------------------------------------------ dynamic scale

__global__ void k_qscale(const f16* __restrict__ qH_, const f16* __restrict__ qL_,
                         const float* __restrict__ scale_w, float* __restrict__ qsc) {
  const int idx = blockIdx.x * blockDim.x + threadIdx.x;  // [0, BH*S)
  if (idx >= CBH * CS) return;
  const int bh = idx >> 10;
  const int h = bh & (CH - 1);
  const f16* ph = qH_ + (size_t)idx * CHD;
  const f16* pl = qL_ + (size_t)idx * CHD;
  const float* sw = scale_w + h * CHD;
  float s = 0.f;
#pragma unroll 8
  for (int j = 0; j < CHD; ++j)
    s += ((float)ph[j] + (float)pl[j] * LO_INV) * sw[j];
  qsc[idx] = 2.f / (1.f + __expf(-s));
}

// ---------------------------------------------------------------- attention

__device__ __forceinline__ int swz(int row, int col) {
  return row * 1024 + (((col >> 2) ^ (row & 7)) << 2) + (col & 3);
}

__global__ __launch_bounds__(256) void k_attn(
    const f16* __restrict__ qH_, const f16* __restrict__ qL_,
    const f16* __restrict__ kH_, const f16* __restrict__ kL_,
    const f16* __restrict__ vTH_, const f16* __restrict__ vTL_,
    const float* __restrict__ qsc,
    f16* __restrict__ aoH, f16* __restrict__ aoL) {
  __shared__ float sc[16 * 1024];  // exactly 64 KiB
  const int bh = blockIdx.y;
  const int b = bh >> 4, h = bh & 15;
  const int q0 = blockIdx.x * 16;
  const int lane = threadIdx.x & 63, wave = threadIdx.x >> 6;
  const int m = lane & 15, quad = lane >> 4;
  const f32x4 VZ = {0.f, 0.f, 0.f, 0.f};

  // --- QK^T ---
  const f16* qrh = qH_ + ((size_t)(bh * CS) + q0 + m) * CHD + quad * 8;
  const f16* qrl = qL_ + ((size_t)(bh * CS) + q0 + m) * CHD + quad * 8;
  f16x8 a0h = *(const f16x8*)(qrh);
  f16x8 a1h = *(const f16x8*)(qrh + 32);
  f16x8 a0l = *(const f16x8*)(qrl);
  f16x8 a1l = *(const f16x8*)(qrl + 32);
  float qs[4];
#pragma unroll
  for (int r = 0; r < 4; ++r) qs[r] = qsc[bh * CS + q0 + quad * 4 + r] * 0.125f;
  for (int kt = wave; kt < 64; kt += 4) {
    const f16* krh = kH_ + ((size_t)(bh * CS) + kt * 16 + m) * CHD + quad * 8;
    const f16* krl = kL_ + ((size_t)(bh * CS) + kt * 16 + m) * CHD + quad * 8;
    f16x8 b0h = *(const f16x8*)(krh);
    f16x8 b1h = *(const f16x8*)(krh + 32);
    f16x8 b0l = *(const f16x8*)(krl);
    f16x8 b1l = *(const f16x8*)(krl + 32);
    f32x4 am = VZ, ac = VZ;
    am = MFMA16(a0h, b0h, am); ac = MFMA16(a0h, b0l, ac); ac = MFMA16(a0l, b0h, ac);
    am = MFMA16(a1h, b1h, am); ac = MFMA16(a1h, b1l, ac); ac = MFMA16(a1l, b1h, ac);
#pragma unroll
    for (int r = 0; r < 4; ++r)
      sc[swz(quad * 4 + r, kt * 16 + m)] = (am[r] + ac[r] * LO_INV) * qs[r];
  }
  __syncthreads();

  // --- softmax (16 threads per row) ---
  {
    const int row = threadIdx.x >> 4, sub = threadIdx.x & 15;
    float mx = -1e30f;
    for (int jj = 0; jj < 64; ++jj) mx = fmaxf(mx, sc[swz(row, sub + jj * 16)]);
#pragma unroll
    for (int msk = 8; msk >= 1; msk >>= 1) mx = fmaxf(mx, __shfl_xor(mx, msk));
    float sum = 0.f;
    for (int jj = 0; jj < 64; ++jj) {
      const int a = swz(row, sub + jj * 16);
      const float e = __expf(sc[a] - mx);
      sc[a] = e; sum += e;
    }
#pragma unroll
    for (int msk = 8; msk >= 1; msk >>= 1) sum += __shfl_xor(sum, msk);
    const float inv = 1.f / sum;
    for (int jj = 0; jj < 64; ++jj) sc[swz(row, sub + jj * 16)] *= inv;
  }
  __syncthreads();

  // --- P @ V (each wave: one 16-col slice of head dim) ---
  const f16* vrh = vTH_ + ((size_t)(bh * CHD) + wave * 16 + m) * CS + quad * 8;
  const f16* vrl = vTL_ + ((size_t)(bh * CHD) + wave * 16 + m) * CS + quad * 8;
  f32x4 accm = VZ, accc = VZ;
  for (int kb = 0; kb < 32; ++kb) {
    const int col0 = kb * 32 + quad * 8;
    float4 p0 = *(const float4*)(sc + swz(m, col0));
    float4 p1 = *(const float4*)(sc + swz(m, col0 + 4));
    float pv[8] = {p0.x, p0.y, p0.z, p0.w, p1.x, p1.y, p1.z, p1.w};
    f16x8 ah, al;
#pragma unroll
    for (int j = 0; j < 8; ++j) {
      f16 hi = (f16)pv[j];
      ah[j] = hi;
      al[j] = (f16)((pv[j] - (float)hi) * LO_SCALE);
    }
    f16x8 bh = *(const f16x8*)(vrh + kb * 32);
    f16x8 bl = *(const f16x8*)(vrl + kb * 32);
    accm = MFMA16(ah, bh, accm);
    accc = MFMA16(ah, bl, accc);
    accc = MFMA16(al, bh, accc);
  }
#pragma unroll
  for (int r = 0; r < 4; ++r) {
    const int srow = q0 + quad * 4 + r;
    const float v = accm[r] + accc[r] * LO_INV;
    f16 hi, lo; fsplit(v, hi, lo);
    const size_t idx = ((size_t)(b * CS + srow)) * CD + h * CHD + wave * 16 + m;
    aoH[idx] = hi; aoL[idx] = lo;
  }
}

// --------------------------------------------------------------- gate / out

__global__ __launch_bounds__(256) void g_gate(
    const f16* __restrict__ aoH, const f16* __restrict__ aoL,
    const f16* __restrict__ gwH, const f16* __restrict__ gwL,
    const float* __restrict__ gate_b,
    f16* __restrict__ gdH, f16* __restrict__ gdL) {
  __shared__ f16 lds[12288];
  const int m0 = blockIdx.x * 64, n0 = blockIdx.y * 128;
  const int t = threadIdx.x;
  const int rowS = t >> 2;
  const int ksw = ((t & 3) ^ ((rowS >> 1) & 3)) * 8;
  const f32x4 VZ = {0.f, 0.f, 0.f, 0.f};
  f32x4 accm[2][4], accc[2][4];
#pragma unroll
  for (int i = 0; i < 2; ++i)
#pragma unroll
    for (int j = 0; j < 4; ++j) { accm[i][j] = VZ; accc[i][j] = VZ; }
  gemm_tile<true>(aoH + (size_t)(m0 + rowS) * CD + ksw,
                  aoL + (size_t)(m0 + rowS) * CD + ksw,
                  gwH + (size_t)(n0 + rowS) * CD + ksw,
                  gwL + (size_t)(n0 + rowS) * CD + ksw,
                  (size_t)64 * CD, CD, lds, accm, accc);
  const int lane = t & 63, wave = t >> 6;
  const int wm = wave >> 1, wn = wave & 1;
  const int m16 = lane & 15, quad = lane >> 4;
#pragma unroll
  for (int sm = 0; sm < 2; ++sm)
#pragma unroll
    for (int sn = 0; sn < 4; ++sn)
#pragma unroll
      for (int r = 0; r < 4; ++r) {
        const int row = m0 + wm * 32 + sm * 16 + quad * 4 + r;
        const int col = n0 + wn * 64 + sn * 16 + m16;
        const float pre = accm[sm][sn][r] + accc[sm][sn][r] * LO_INV + gate_b[col];
        const float g = 1.f / (1.f + __expf(-pre));
        const size_t idx = (size_t)row * CD + col;
        const float ov = (float)aoH[idx] + (float)aoL[idx] * LO_INV;
        f16 hi, lo; fsplit(ov * g, hi, lo);
        gdH[idx] = hi; gdL[idx] = lo;
      }
}

__global__ __launch_bounds__(256) void g_outp(
    const f16* __restrict__ gdH, const f16* __restrict__ gdL,
    const f16* __restrict__ owH, const f16* __restrict__ owL,
    const float* __restrict__ src, float* __restrict__ y1) {
  __shared__ f16 lds[12288];
  const int m0 = blockIdx.x * 64, n0 = blockIdx.y * 128;
  const int t = threadIdx.x;
  const int rowS = t >> 2;
  const int ksw = ((t & 3) ^ ((rowS >> 1) & 3)) * 8;
  const f32x4 VZ = {0.f, 0.f, 0.f, 0.f};
  f32x4 accm[2][4], accc[2][4];
#pragma unroll
  for (int i = 0; i < 2; ++i)
#pragma unroll
    for (int j = 0; j < 4; ++j) { accm[i][j] = VZ; accc[i][j] = VZ; }
  gemm_tile<true>(gdH + (size_t)(m0 + rowS) * CD + ksw,
                  gdL + (size_t)(m0 + rowS) * CD + ksw,
                  owH + (size_t)(n0 + rowS) * CD + ksw,
                  owL + (size_t)(n0 + rowS) * CD + ksw,
                  (size_t)64 * CD, CD, lds, accm, accc);
  const int lane = t & 63, wave = t >> 6;
  const int wm = wave >> 1, wn = wave & 1;
  const int m16 = lane & 15, quad = lane >> 4;
#pragma unroll
  for (int sm = 0; sm < 2; ++sm)
#pragma unroll
    for (int sn = 0; sn < 4; ++sn)
#pragma unroll
      for (int r = 0; r < 4; ++r) {
        const int row = m0 + wm * 32 + sm * 16 + quad * 4 + r;
        const int col = n0 + wn * 64 + sn * 16 + m16;
        const size_t idx = (size_t)row * CD + col;
        y1[idx] = src[idx] + accm[sm][sn][r] + accc[sm][sn][r] * LO_INV;
      }
}

// -------------------------------------------------------------- layernorms

__device__ __forceinline__ void block_reduce2(float &s, float &ss, float* red) {
#pragma unroll
  for (int msk = 32; msk >= 1; msk >>= 1) {
    s += __shfl_xor(s, msk);
    ss += __shfl_xor(ss, msk);
  }
  const int wave = threadIdx.x >> 6, lane = threadIdx.x & 63;
  if (lane == 0) { red[wave] = s; red[4 + wave] = ss; }
  __syncthreads();
  s = red[0] + red[1] + red[2] + red[3];
  ss = red[4] + red[5] + red[6] + red[7];
}

__global__ __launch_bounds__(256) void k_ln1(
    const float* __restrict__ y1, const float* __restrict__ g, const float* __restrict__ bb,
    float* __restrict__ x, f16* __restrict__ xH) {
  __shared__ float red[8];
  const int n = blockIdx.x;
  const float* row = y1 + (size_t)n * CD;
  const int t = threadIdx.x;
  float4 v = *(const float4*)(row + t * 4);
  float a[4] = {v.x, v.y, v.z, v.w};
  float s = a[0] + a[1] + a[2] + a[3];
  float ss = a[0]*a[0] + a[1]*a[1] + a[2]*a[2] + a[3]*a[3];
  block_reduce2(s, ss, red);
  const float mean = s * (1.f / CD);
  const float var = ss * (1.f / CD) - mean * mean;
  const float rstd = rsqrtf(var + 1e-5f);
#pragma unroll
  for (int j = 0; j < 4; ++j) {
    const int d = t * 4 + j;
    const float val = (a[j] - mean) * rstd * g[d] + bb[d];
    x[(size_t)n * CD + d] = val;
    xH[(size_t)n * CD + d] = (f16)val;
  }
}

__global__ __launch_bounds__(256) void k_ln2(
    const float* __restrict__ z, const float* __restrict__ g, const float* __restrict__ bb,
    float* __restrict__ outp) {
  __shared__ float red[8];
  const int n = blockIdx.x;
  const float* row = z + (size_t)n * CD;
  const int t = threadIdx.x;
  float4 v = *(const float4*)(row + t * 4);
  float a[4] = {v.x, v.y, v.z, v.w};
  float s = a[0] + a[1] + a[2] + a[3];
  float ss = a[0]*a[0] + a[1]*a[1] + a[2]*a[2] + a[3]*a[3];
  block_reduce2(s, ss, red);
  const float mean = s * (1.f / CD);
  const float var = ss * (1.f / CD) - mean * mean;
  const float rstd = rsqrtf(var + 1e-5f);
#pragma unroll
  for (int j = 0; j < 4; ++j) {
    const int d = t * 4 + j;
    outp[(size_t)n * CD + d] = (a[j] - mean) * rstd * g[d] + bb[d];
  }
}

// ------------------------------------------------------------------ routing

__global__ void k_zero_counts(int* counts) {
  if (threadIdx.x < CE) counts[threadIdx.x] = 0;
}

__global__ __launch_bounds__(256) void k_route(
    const float* __restrict__ x, const float* __restrict__ gw, const float* __restrict__ gb,
    int* __restrict__ chosen, int* __restrict__ counts, int* __restrict__ bucket) {
  const int wave = threadIdx.x >> 6, lane = threadIdx.x & 63;
  const int n = blockIdx.x * 4 + wave;
  const float* xr = x + (size_t)n * CD;
  float acc[CE];
#pragma unroll
  for (int e = 0; e < CE; ++e) acc[e] = 0.f;
  for (int j = 0; j < 16; ++j) {
    const int d = lane * 16 + j;
    const float xv = xr[d];
    const float* wr = gw + (size_t)d * CE;
#pragma unroll
    for (int e = 0; e < CE; ++e) acc[e] += xv * wr[e];
  }
#pragma unroll
  for (int msk = 32; msk >= 1; msk >>= 1) {
#pragma unroll
    for (int e = 0; e < CE; ++e) acc[e] += __shfl_xor(acc[e], msk);
  }
  if (lane == 0) {
    float best = -1e30f, second = -1e30f;
    int bi = 0, si = 0;
#pragma unroll
    for (int e = 0; e < CE; ++e) {
      const float L = acc[e] + gb[e];
      if (L > best) { second = best; si = bi; best = L; bi = e; }
      else if (L > second) { second = L; si = e; }
    }
    const int ch = bi > si ? bi : si;  // torch-loop semantics: max index wins
    chosen[n] = ch;
    const int pos = atomicAdd(&counts[ch], 1);
    bucket[ch * CN + pos] = n;
  }
}

// ------------------------------------------------------------------ MoE FFN

__global__ __launch_bounds__(256) void g_moe1(
    const f16* __restrict__ xH, const f16* __restrict__ w1t,
    const float* __restrict__ b1, const int* __restrict__ counts,
    const int* __restrict__ bucket, float* __restrict__ hb) {
  const int e = blockIdx.z;
  const int cnt = counts[e];
  const int m0 = blockIdx.x * 64;
  if (m0 >= cnt) return;
  __shared__ f16 lds[6144];
  const int t = threadIdx.x;
  const int rowS = t >> 2;
  const int ksw = ((t & 3) ^ ((rowS >> 1) & 3)) * 8;
  int ra = m0 + rowS; if (ra > cnt - 1) ra = cnt - 1;
  const int tokA = bucket[e * CN + ra];
  const int n0 = blockIdx.y * 128;
  const f32x4 VZ = {0.f, 0.f, 0.f, 0.f};
  f32x4 accm[2][4];
#pragma unroll
  for (int i = 0; i < 2; ++i)
#pragma unroll
    for (int j = 0; j < 4; ++j) accm[i][j] = VZ;
  gemm_tile<false>(xH + (size_t)tokA * CD + ksw, nullptr,
                   w1t + ((size_t)e * CF + n0 + rowS) * CD + ksw, nullptr,
                   (size_t)64 * CD, CD, lds, accm, accm);
  const int lane = t & 63, wave = t >> 6;
  const int wm = wave >> 1, wn = wave & 1;
  const int m16 = lane & 15, quad = lane >> 4;
#pragma unroll
  for (int sm = 0; sm < 2; ++sm)
#pragma unroll
    for (int sn = 0; sn < 4; ++sn)
#pragma unroll
      for (int r = 0; r < 4; ++r) {
        const int rr = m0 + wm * 32 + sm * 16 + quad * 4 + r;
        if (rr >= cnt) continue;
        const int tok = bucket[e * CN + rr];
        const int col = n0 + wn * 64 + sn * 16 + m16;
        hb[(size_t)tok * CF + col] = accm[sm][sn][r] + b1[e * CF + col];
      }
}

__global__ __launch_bounds__(256) void k_lngelu(
    const float* __restrict__ hb, const int* __restrict__ chosen,
    const float* __restrict__ ln_g, const float* __restrict__ ln_b,
    f16* __restrict__ h2) {
  __shared__ float red[8];
  const int n = blockIdx.x;
  const int e = chosen[n];
  const float* row = hb + (size_t)n * CF;
  const int t = threadIdx.x;
  float4 v0 = *(const float4*)(row + t * 8);
  float4 v1 = *(const float4*)(row + t * 8 + 4);
  float a[8] = {v0.x, v0.y, v0.z, v0.w, v1.x, v1.y, v1.z, v1.w};
  float s = 0.f, ss = 0.f;
#pragma unroll
  for (int j = 0; j < 8; ++j) { s += a[j]; ss += a[j] * a[j]; }
  block_reduce2(s, ss, red);
  const float mean = s * (1.f / CF);
  const float var = ss * (1.f / CF) - mean * mean;
  const float rstd = rsqrtf(var + 1e-5f);
  const float* g = ln_g + (size_t)e * CF;
  const float* bb = ln_b + (size_t)e * CF;
#pragma unroll
  for (int j = 0; j < 8; ++j) {
    const int d = t * 8 + j;
    const float val = (a[j] - mean) * rstd * g[d] + bb[d];
    const float gl = 0.5f * val * (1.f + erff(val * 0.70710678118654752f));
    h2[(size_t)n * CF + d] = (f16)gl;
  }
}

__global__ __launch_bounds__(256) void g_moe2(
    const f16* __restrict__ h2, const f16* __restrict__ w2t,
    const float* __restrict__ b2, const float* __restrict__ rsc,
    const int* __restrict__ counts, const int* __restrict__ bucket,
    const float* __restrict__ x, float* __restrict__ z) {
  const int e = blockIdx.z;
  const int cnt = counts[e];
  const int m0 = blockIdx.x * 64;
  if (m0 >= cnt) return;
  __shared__ f16 lds[6144];
  const int t = threadIdx.x;
  const int rowS = t >> 2;
  const int ksw = ((t & 3) ^ ((rowS >> 1) & 3)) * 8;
  int ra = m0 + rowS; if (ra > cnt - 1) ra = cnt - 1;
  const int tokA = bucket[e * CN + ra];
  const int n0 = blockIdx.y * 128;
  const f32x4 VZ = {0.f, 0.f, 0.f, 0.f};
  f32x4 accm[2][4];
#pragma unroll
  for (int i = 0; i < 2; ++i)
#pragma unroll
    for (int j = 0; j < 4; ++j) accm[i][j] = VZ;
  gemm_tile<false>(h2 + (size_t)tokA * CF + ksw, nullptr,
                   w2t + ((size_t)e * CD + n0 + rowS) * CF + ksw, nullptr,
                   (size_t)64 * CF, CF, lds, accm, accm);
  const float rs = rsc[e];
  const int lane = t & 63, wave = t >> 6;
  const int wm = wave >> 1, wn = wave & 1;
  const int m16 = lane & 15, quad = lane >> 4;
#pragma unroll
  for (int sm = 0; sm < 2; ++sm)
#pragma unroll
    for (int sn = 0; sn < 4; ++sn)
#pragma unroll
      for (int r = 0; r < 4; ++r) {
        const int rr = m0 + wm * 32 + sm * 16 + quad * 4 + r;
        if (rr >= cnt) continue;
        const int tok = bucket[e * CN + rr];
        const int col = n0 + wn * 64 + sn * 16 + m16;
        const size_t idx = (size_t)tok * CD + col;
        // z = x + moe ; moe = (h2@W2 + b2)*rsc + x   (top-2 weight sum == 1)
        z[idx] = 2.f * x[idx] + (accm[sm][sn][r] + b2[e * CD + col]) * rs;
      }
}

// ------------------------------------------------------------------- launch

extern "C" void kernel_launch(void* const* d_in, const int* in_sizes, int n_in,
                              void* d_out, int out_size, void* d_ws, size_t ws_size,
                              hipStream_t stream) {
  (void)in_sizes; (void)n_in; (void)out_size; (void)ws_size;
  const float* src        = (const float*)d_in[0];
  const float* q_w        = (const float*)d_in[1];
  const float* k_w        = (const float*)d_in[2];
  const float* v_w        = (const float*)d_in[3];
  const float* out_w      = (const float*)d_in[4];
  const float* gate_w     = (const float*)d_in[5];
  const float* gate_b     = (const float*)d_in[6];
  const float* scale_w    = (const float*)d_in[7];
  const float* n1_g       = (const float*)d_in[8];
  const float* n1_b       = (const float*)d_in[9];
  const float* n2_g       = (const float*)d_in[10];
  const float* n2_b       = (const float*)d_in[11];
  const float* moe_gate_w = (const float*)d_in[12];
  const float* moe_gate_b = (const float*)d_in[13];
  const float* w1         = (const float*)d_in[14];
  const float* b1         = (const float*)d_in[15];
  const float* ln_g       = (const float*)d_in[16];
  const float* ln_b       = (const float*)d_in[17];
  const float* w2         = (const float*)d_in[18];
  const float* b2         = (const float*)d_in[19];
  const float* res_scale  = (const float*)d_in[20];
  float* outp = (float*)d_out;

  char* p = (char*)d_ws;
  auto take = [&](size_t bytes) -> char* {
    char* r = p;
    p += (bytes + 255) & ~(size_t)255;
    return r;
  };
  f16* srcH = (f16*)take((size_t)CN * CD * 2);
  f16* srcL = (f16*)take((size_t)CN * CD * 2);
  f16* qwH = (f16*)take((size_t)CD * CD * 2);
  f16* qwL = (f16*)take((size_t)CD * CD * 2);
  f16* kwH = (f16*)take((size_t)CD * CD * 2);
  f16* kwL = (f16*)take((size_t)CD * CD * 2);
  f16* vwH = (f16*)take((size_t)CD * CD * 2);
  f16* vwL = (f16*)take((size_t)CD * CD * 2);
  f16* gwH = (f16*)take((size_t)CD * CD * 2);
  f16* gwL = (f16*)take((size_t)CD * CD * 2);
  f16* owH = (f16*)take((size_t)CD * CD * 2);
  f16* owL = (f16*)take((size_t)CD * CD * 2);
  f16* qH = (f16*)take((size_t)CBH * CS * CHD * 2);
  f16* qL = (f16*)take((size_t)CBH * CS * CHD * 2);
  f16* kH = (f16*)take((size_t)CBH * CS * CHD * 2);
  f16* kL = (f16*)take((size_t)CBH * CS * CHD * 2);
  f16* vTH = (f16*)take((size_t)CBH * CS * CHD * 2);
  f16* vTL = (f16*)take((size_t)CBH * CS * CHD * 2);
  float* qsc = (float*)take((size_t)CBH * CS * 4);
  f16* aoH = (f16*)take((size_t)CN * CD * 2);
  f16* aoL = (f16*)take((size_t)CN * CD * 2);
  f16* gdH = (f16*)take((size_t)CN * CD * 2);
  f16* gdL = (f16*)take((size_t)CN * CD * 2);
  float* y1 = (float*)take((size_t)CN * CD * 4);
  float* x  = (float*)take((size_t)CN * CD * 4);
  f16* xH = (f16*)take((size_t)CN * CD * 2);
  int* counts = (int*)take(64);
  int* bucket = (int*)take((size_t)CE * CN * 4);
  int* chosen = (int*)take((size_t)CN * 4);
  float* hb = (float*)take((size_t)CN * CF * 4);
  f16* h2 = (f16*)take((size_t)CN * CF * 2);
  f16* w1t = (f16*)take((size_t)CE * CF * CD * 2);
  f16* w2t = (f16*)take((size_t)CE * CD * CF * 2);
  float* zb = (float*)take((size_t)CN * CD * 4);

  // --- input conversion / weight transposition ---
  k_split_cvt<<<dim3(CN * CD / 4 / 256), 256, 0, stream>>>(src, srcH, srcL, CN * CD);
  dim3 tb(32, 8);
  k_transpose_split<<<dim3(CD / 32, CD / 32, 1), tb, 0, stream>>>(q_w, qwH, qwL, CD, CD);
  k_transpose_split<<<dim3(CD / 32, CD / 32, 1), tb, 0, stream>>>(k_w, kwH, kwL, CD, CD);
  k_transpose_split<<<dim3(CD / 32, CD / 32, 1), tb, 0, stream>>>(v_w, vwH, vwL, CD, CD);
  k_transpose_split<<<dim3(CD / 32, CD / 32, 1), tb, 0, stream>>>(gate_w, gwH, gwL, CD, CD);
  k_transpose_split<<<dim3(CD / 32, CD / 32, 1), tb, 0, stream>>>(out_w, owH, owL, CD, CD);
  k_transpose_split<<<dim3(CF / 32, CD / 32, CE), tb, 0, stream>>>(w1, w1t, nullptr, CD, CF);
  k_transpose_split<<<dim3(CD / 32, CF / 32, CE), tb, 0, stream>>>(w2, w2t, nullptr, CF, CD);

  // --- attention ---
  g_qkv<<<dim3(CN / 64, CD / 128, 3), 256, 0, stream>>>(
      srcH, srcL, qwH, qwL, kwH, kwL, vwH, vwL, qH, qL, kH, kL, vTH, vTL);
  k_qscale<<<dim3(CBH * CS / 256), 256, 0, stream>>>(qH, qL, scale_w, qsc);
  k_attn<<<dim3(CS / 16, CBH), 256, 0, stream>>>(qH, qL, kH, kL, vTH, vTL, qsc, aoH, aoL);
  g_gate<<<dim3(CN / 64, CD / 128), 256, 0, stream>>>(aoH, aoL, gwH, gwL, gate_b, gdH, gdL);
  g_outp<<<dim3(CN / 64, CD / 128), 256, 0, stream>>>(gdH, gdL, owH, owL, src, y1);
  k_ln1<<<dim3(CN), 256, 0, stream>>>(y1, n1_g, n1_b, x, xH);

  // --- routing + MoE ---
  k_zero_counts<<<dim3(1), 64, 0, stream>>>(counts);
  k_route<<<dim3(CN / 4), 256, 0, stream>>>(x, moe_gate_w, moe_gate_b, chosen, counts, bucket);
  g_moe1<<<dim3(CN / 64, CF / 128, CE), 256, 0, stream>>>(xH, w1t, b1, counts, bucket, hb);
  k_lngelu<<<dim3(CN), 256, 0, stream>>>(hb, chosen, ln_g, ln_b, h2);
  g_moe2<<<dim3(CN / 64, CD / 128, CE), 256, 0, stream>>>(h2, w2t, b2, res_scale, counts, bucket, x, zb);
  k_ln2<<<dim3(CN), 256, 0, stream>>>(zb, n2_g, n2_b, outp);
}

// Round 3
// 777.952 us; speedup vs baseline: 1.6331x; 1.0232x over previous
//
#include <hip/hip_runtime.h>

// MemoAI fused block for MI355X (gfx950).
//  - fp16x2 split-precision MFMA (hi + 2^11-scaled lo) upstream of MoE routing
//  - plain fp16 MFMA for the expert FFN (post-routing)
//  - sum(softmax(top2)) == 1 -> moe weight multiplier is exactly 1
//  - only the chosen expert is computed (tokens bucketed by expert)
//  - R1: all GEMMs use a 64x128 LDS-staged core (global_load_lds width=16)
//  - R2: flash-style attention (online softmax, register scores, wave-private
//    4KB swizzled LDS for the P C->A-layout transpose), qscale fused in.

typedef _Float16 f16;
typedef _Float16 f16x8 __attribute__((ext_vector_type(8)));
typedef float f32x4 __attribute__((ext_vector_type(4)));

constexpr int CS  = 1024;  // seq len
constexpr int CD  = 1024;  // model dim
constexpr int CH  = 16;    // heads
constexpr int CHD = 64;    // head dim
constexpr int CF  = 2048;  // ffn dim
constexpr int CE  = 8;     // experts
constexpr int CN  = 2048;  // tokens = B*S
constexpr int CBH = 32;    // B*H

constexpr float LO_SCALE = 2048.f;       // 2^11: keeps lo-parts normal in fp16
constexpr float LO_INV   = 1.f / 2048.f;

#define MFMA16(a, b, c) __builtin_amdgcn_mfma_f32_16x16x32_f16((a), (b), (c), 0, 0, 0)

#define TO_GBL(p) ((const __attribute__((address_space(1))) void*)(p))
#define TO_LDS(p) ((__attribute__((address_space(3))) void*)(p))
#define GLD16(g, l) __builtin_amdgcn_global_load_lds(TO_GBL(g), TO_LDS(l), 16, 0, 0)

__device__ __forceinline__ void fsplit(float v, f16 &hi, f16 &lo) {
  hi = (f16)v;
  lo = (f16)((v - (float)hi) * LO_SCALE);
}

// ---------------------------------------------------------------- conversions

__global__ void k_split_cvt(const float* __restrict__ in, f16* __restrict__ oh,
                            f16* __restrict__ ol, int n) {
  int i = (blockIdx.x * blockDim.x + threadIdx.x) * 4;
  if (i >= n) return;
  float4 v = *(const float4*)(in + i);
  float a[4] = {v.x, v.y, v.z, v.w};
#pragma unroll
  for (int j = 0; j < 4; ++j) {
    f16 hi = (f16)a[j];
    oh[i + j] = hi;
    ol[i + j] = (f16)((a[j] - (float)hi) * LO_SCALE);
  }
}

// in: [Z][R][C] f32 -> outH(/outL scaled) : [Z][C][R] f16
__global__ void k_transpose_split(const float* __restrict__ in, f16* __restrict__ oh,
                                  f16* __restrict__ ol, int R, int C) {
  __shared__ float t[32][33];
  const int z = blockIdx.z;
  const float* src = in + (size_t)z * R * C;
  f16* dh = oh + (size_t)z * R * C;
  f16* dl = ol ? ol + (size_t)z * R * C : nullptr;
  const int c0 = blockIdx.x * 32, r0 = blockIdx.y * 32;
  const int tx = threadIdx.x, ty = threadIdx.y;
#pragma unroll
  for (int i = 0; i < 32; i += 8)
    t[ty + i][tx] = src[(size_t)(r0 + ty + i) * C + c0 + tx];
  __syncthreads();
#pragma unroll
  for (int i = 0; i < 32; i += 8) {
    float v = t[tx][ty + i];
    f16 hi = (f16)v;
    size_t idx = (size_t)(c0 + ty + i) * R + r0 + tx;
    dh[idx] = hi;
    if (dl) dl[idx] = (f16)((v - (float)hi) * LO_SCALE);
  }
}

// ------------------------------------------------------------- tiled GEMM core
// Block tile 64(M) x 128(N), BK=32, 4 waves (2x2), wave tile 32x64.

template <bool SPLIT>
__device__ __forceinline__ void gemm_tile(
    const f16* aH, const f16* aL, const f16* bH, const f16* bL,
    size_t bRowStride /* 64*ldb */, int K, f16* lds,
    f32x4 (&accm)[2][4], f32x4 (&accc)[2][4]) {
  f16* lAh = lds;                          // 64*32  = 2048 halves
  f16* lAl = lds + 2048;                   // (split only)
  f16* lBh = lds + (SPLIT ? 4096 : 2048);  // 128*32 = 4096 halves
  f16* lBl = lds + 8192;                   // (split only)
  const int t = threadIdx.x;
  const int lane = t & 63, wave = t >> 6;
  const int wm = wave >> 1, wn = wave & 1;
  const int m16 = lane & 15, quad = lane >> 4;
  int aoff[2], boff[4];
#pragma unroll
  for (int sm = 0; sm < 2; ++sm) {
    const int r = wm * 32 + sm * 16 + m16;
    aoff[sm] = r * 32 + ((quad ^ ((r >> 1) & 3)) * 8);
  }
#pragma unroll
  for (int sn = 0; sn < 4; ++sn) {
    const int r = wn * 64 + sn * 16 + m16;
    boff[sn] = r * 32 + ((quad ^ ((r >> 1) & 3)) * 8);
  }
  for (int k = 0; k < K; k += 32) {
    GLD16(aH, lAh + t * 8);
    GLD16(bH, lBh + t * 8);
    GLD16(bH + bRowStride, lBh + 2048 + t * 8);
    if constexpr (SPLIT) {
      GLD16(aL, lAl + t * 8);
      GLD16(bL, lBl + t * 8);
      GLD16(bL + bRowStride, lBl + 2048 + t * 8);
      aL += 32; bL += 32;
    }
    aH += 32; bH += 32;
    __syncthreads();  // drains vmcnt(0) -> staged data visible
    f16x8 af[2], alf[2], bf[4], blf[4];
#pragma unroll
    for (int sm = 0; sm < 2; ++sm) {
      af[sm] = *(const f16x8*)(lAh + aoff[sm]);
      if constexpr (SPLIT) alf[sm] = *(const f16x8*)(lAl + aoff[sm]);
    }
#pragma unroll
    for (int sn = 0; sn < 4; ++sn) {
      bf[sn] = *(const f16x8*)(lBh + boff[sn]);
      if constexpr (SPLIT) blf[sn] = *(const f16x8*)(lBl + boff[sn]);
    }
#pragma unroll
    for (int sm = 0; sm < 2; ++sm)
#pragma unroll
      for (int sn = 0; sn < 4; ++sn) {
        accm[sm][sn] = MFMA16(af[sm], bf[sn], accm[sm][sn]);
        if constexpr (SPLIT) {
          accc[sm][sn] = MFMA16(af[sm], blf[sn], accc[sm][sn]);
          accc[sm][sn] = MFMA16(alf[sm], bf[sn], accc[sm][sn]);
        }
      }
    __syncthreads();  // all waves done reading before next overwrite
  }
}

// ---------------------------------------------------------------- QKV

__global__ __launch_bounds__(256) void g_qkv(
    const f16* __restrict__ srcH, const f16* __restrict__ srcL,
    const f16* __restrict__ qwH, const f16* __restrict__ qwL,
    const f16* __restrict__ kwH, const f16* __restrict__ kwL,
    const f16* __restrict__ vwH, const f16* __restrict__ vwL,
    f16* __restrict__ qHo, f16* __restrict__ qLo,
    f16* __restrict__ kHo, f16* __restrict__ kLo,
    f16* __restrict__ vTH, f16* __restrict__ vTL) {
  __shared__ f16 lds[12288];
  const int z = blockIdx.z;
  const int m0 = blockIdx.x * 64, n0 = blockIdx.y * 128;
  const int t = threadIdx.x;
  const int rowS = t >> 2;
  const int ksw = ((t & 3) ^ ((rowS >> 1) & 3)) * 8;
  const f16* BH = (z == 0) ? qwH : (z == 1) ? kwH : vwH;
  const f16* BL = (z == 0) ? qwL : (z == 1) ? kwL : vwL;
  const f32x4 VZ = {0.f, 0.f, 0.f, 0.f};
  f32x4 accm[2][4], accc[2][4];
#pragma unroll
  for (int i = 0; i < 2; ++i)
#pragma unroll
    for (int j = 0; j < 4; ++j) { accm[i][j] = VZ; accc[i][j] = VZ; }
  gemm_tile<true>(srcH + (size_t)(m0 + rowS) * CD + ksw,
                  srcL + (size_t)(m0 + rowS) * CD + ksw,
                  BH + (size_t)(n0 + rowS) * CD + ksw,
                  BL + (size_t)(n0 + rowS) * CD + ksw,
                  (size_t)64 * CD, CD, lds, accm, accc);
  const int lane = t & 63, wave = t >> 6;
  const int wm = wave >> 1, wn = wave & 1;
  const int m16 = lane & 15, quad = lane >> 4;
#pragma unroll
  for (int sm = 0; sm < 2; ++sm)
#pragma unroll
    for (int sn = 0; sn < 4; ++sn)
#pragma unroll
      for (int r = 0; r < 4; ++r) {
        const int row = m0 + wm * 32 + sm * 16 + quad * 4 + r;  // token
        const int col = n0 + wn * 64 + sn * 16 + m16;           // d
        const float v = accm[sm][sn][r] + accc[sm][sn][r] * LO_INV;
        f16 hi, lo; fsplit(v, hi, lo);
        const int bb = row >> 10, ss = row & 1023;
        const int hh = col >> 6, hd = col & 63;
        if (z == 2) {  // v stored transposed: [b,h,hd,s]
          const size_t idx = ((size_t)((bb * CH + hh) * CHD + hd)) * CS + ss;
          vTH[idx] = hi; vTL[idx] = lo;
        } else {
          const size_t idx = ((size_t)((bb * CH + hh) * CS + ss)) * CHD + hd;
          if (z == 0) { qHo[idx] = hi; qLo[idx] = lo; }
          else        { kHo[idx] = hi; kLo[idx] = lo; }
        }
      }
}

// ------------------------------------------------------- flash attention
// Block = 64 q-rows of one (b,h); 4 waves, each owns 16 q-rows and streams
// all 1024 keys in 64-key chunks with online softmax. P transposed from
// MFMA C-layout to A-layout through a wave-private 4KB XOR-swizzled LDS tile.
// Dynamic scale (sigmoid(q.scale_w)*2) computed in-prologue from Q frags.

__device__ __forceinline__ int pswz(int q, int k) {
  return q * 64 + ((((k >> 2) ^ q) & 15) << 2) + (k & 3);
}

__global__ __launch_bounds__(256) void k_fattn(
    const f16* __restrict__ qH_, const f16* __restrict__ qL_,
    const f16* __restrict__ kH_, const f16* __restrict__ kL_,
    const f16* __restrict__ vTH_, const f16* __restrict__ vTL_,
    const float* __restrict__ scale_w,
    f16* __restrict__ aoH, f16* __restrict__ aoL) {
  __shared__ float psc[4 * 1024];  // 4 waves x (16x64) P tile, swizzled
  const int bh = blockIdx.y;
  const int b = bh >> 4, h = bh & 15;
  const int lane = threadIdx.x & 63, wave = threadIdx.x >> 6;
  const int m16 = lane & 15, quad = lane >> 4;
  const int q0 = blockIdx.x * 64 + wave * 16;  // this wave's q rows
  float* P = psc + wave * 1024;
  const f32x4 VZ = {0.f, 0.f, 0.f, 0.f};

  // Q fragments (A-layout): row q0+m16, k = hd (two 32-chunks), hi+lo
  const f16* qrh = qH_ + ((size_t)bh * CS + q0 + m16) * CHD + quad * 8;
  const f16* qrl = qL_ + ((size_t)bh * CS + q0 + m16) * CHD + quad * 8;
  f16x8 a0h = *(const f16x8*)(qrh);
  f16x8 a1h = *(const f16x8*)(qrh + 32);
  f16x8 a0l = *(const f16x8*)(qrl);
  f16x8 a1l = *(const f16x8*)(qrl + 32);

  // fused dynamic scale: row factor = 2*sigmoid(q . scale_w[h]) / sqrt(64)
  float dot = 0.f;
  {
    const float* sw = scale_w + h * CHD + quad * 8;
    float4 s0 = *(const float4*)(sw);
    float4 s1 = *(const float4*)(sw + 4);
    float4 s2 = *(const float4*)(sw + 32);
    float4 s3 = *(const float4*)(sw + 36);
    float sv[16] = {s0.x, s0.y, s0.z, s0.w, s1.x, s1.y, s1.z, s1.w,
                    s2.x, s2.y, s2.z, s2.w, s3.x, s3.y, s3.z, s3.w};
#pragma unroll
    for (int j = 0; j < 8; ++j) {
      dot += ((float)a0h[j] + (float)a0l[j] * LO_INV) * sv[j];
      dot += ((float)a1h[j] + (float)a1l[j] * LO_INV) * sv[8 + j];
    }
    dot += __shfl_xor(dot, 16);
    dot += __shfl_xor(dot, 32);
  }
  const float qsv = 2.f / (1.f + __expf(-dot));  // for row q0+m16
  float qsr[4];
#pragma unroll
  for (int r = 0; r < 4; ++r) qsr[r] = __shfl(qsv, quad * 4 + r) * 0.125f;

  f32x4 accm[4], accc[4];  // out accumulator: 4 hd-tiles, C-layout
#pragma unroll
  for (int t = 0; t < 4; ++t) { accm[t] = VZ; accc[t] = VZ; }
  float mrun[4], lrun[4];
#pragma unroll
  for (int r = 0; r < 4; ++r) { mrun[r] = -1e30f; lrun[r] = 0.f; }

  for (int kc = 0; kc < CS; kc += 64) {
    // --- S = (Q K^T) * qs for 4 key tiles (C-layout, fp32-exact via split)
    f32x4 st[4];
#pragma unroll
    for (int t = 0; t < 4; ++t) {
      const f16* krh = kH_ + ((size_t)bh * CS + kc + t * 16 + m16) * CHD + quad * 8;
      const f16* krl = kL_ + ((size_t)bh * CS + kc + t * 16 + m16) * CHD + quad * 8;
      f16x8 b0h = *(const f16x8*)(krh);
      f16x8 b1h = *(const f16x8*)(krh + 32);
      f16x8 b0l = *(const f16x8*)(krl);
      f16x8 b1l = *(const f16x8*)(krl + 32);
      f32x4 am = VZ, ac = VZ;
      am = MFMA16(a0h, b0h, am); am = MFMA16(a1h, b1h, am);
      ac = MFMA16(a0h, b0l, ac); ac = MFMA16(a0l, b0h, ac);
      ac = MFMA16(a1h, b1l, ac); ac = MFMA16(a1l, b1h, ac);
#pragma unroll
      for (int r = 0; r < 4; ++r)
        st[t][r] = (am[r] + ac[r] * LO_INV) * qsr[r];
    }
    // --- online max update (rows live across the 16 lanes of each quad)
    float alpha[4];
#pragma unroll
    for (int r = 0; r < 4; ++r) {
      float mx = fmaxf(fmaxf(st[0][r], st[1][r]), fmaxf(st[2][r], st[3][r]));
#pragma unroll
      for (int msk = 8; msk >= 1; msk >>= 1) mx = fmaxf(mx, __shfl_xor(mx, msk));
      const float mnew = fmaxf(mrun[r], mx);
      alpha[r] = __expf(mrun[r] - mnew);
      mrun[r] = mnew;
    }
    // --- exp, row-sum, stash P (C-layout) into swizzled LDS
    float rs[4] = {0.f, 0.f, 0.f, 0.f};
#pragma unroll
    for (int t = 0; t < 4; ++t)
#pragma unroll
      for (int r = 0; r < 4; ++r) {
        const float e = __expf(st[t][r] - mrun[r]);
        rs[r] += e;
        P[pswz(quad * 4 + r, t * 16 + m16)] = e;
      }
#pragma unroll
    for (int r = 0; r < 4; ++r) {
#pragma unroll
      for (int msk = 8; msk >= 1; msk >>= 1) rs[r] += __shfl_xor(rs[r], msk);
      lrun[r] = lrun[r] * alpha[r] + rs[r];
#pragma unroll
      for (int t = 0; t < 4; ++t) { accm[t][r] *= alpha[r]; accc[t][r] *= alpha[r]; }
    }
    // --- read P back in A-layout, split hi/lo
    f16x8 pah[2], pal[2];
#pragma unroll
    for (int c = 0; c < 2; ++c) {
      const int k0 = c * 32 + quad * 8;
      float4 p0 = *(const float4*)(P + pswz(m16, k0));
      float4 p1 = *(const float4*)(P + pswz(m16, k0 + 4));
      float pv[8] = {p0.x, p0.y, p0.z, p0.w, p1.x, p1.y, p1.z, p1.w};
#pragma unroll
      for (int j = 0; j < 8; ++j) {
        f16 hi = (f16)pv[j];
        pah[c][j] = hi;
        pal[c][j] = (f16)((pv[j] - (float)hi) * LO_SCALE);
      }
    }
    // --- O += P V  (V^T B-frags straight from the [b,h,hd,s] layout)
#pragma unroll
    for (int t = 0; t < 4; ++t) {
      const f16* vrh = vTH_ + ((size_t)bh * CHD + t * 16 + m16) * CS + kc + quad * 8;
      const f16* vrl = vTL_ + ((size_t)bh * CHD + t * 16 + m16) * CS + kc + quad * 8;
#pragma unroll
      for (int c = 0; c < 2; ++c) {
        f16x8 vbh = *(const f16x8*)(vrh + c * 32);
        f16x8 vbl = *(const f16x8*)(vrl + c * 32);
        accm[t] = MFMA16(pah[c], vbh, accm[t]);
        accc[t] = MFMA16(pah[c], vbl, accc[t]);
        accc[t] = MFMA16(pal[c], vbh, accc[t]);
      }
    }
  }
  // --- epilogue: normalize by l, split-store
#pragma unroll
  for (int t = 0; t < 4; ++t)
#pragma unroll
    for (int r = 0; r < 4; ++r) {
      const int row = q0 + quad * 4 + r;
      const float v = (accm[t][r] + accc[t][r] * LO_INV) / lrun[r];
      f16 hi, lo; fsplit(v, hi, lo);
      const size_t idx = ((size_t)(b * CS + row)) * CD + h * CHD + t * 16 + m16;
      aoH[idx] = hi; aoL[idx] = lo;
    }
}

// --------------------------------------------------------------- gate / out

__global__ __launch_bounds__(256) void g_gate(
    const f16* __restrict__ aoH, const f16* __restrict__ aoL,
    const f16* __restrict__ gwH, const f16* __restrict__ gwL,
    const float* __restrict__ gate_b,
    f16* __restrict__ gdH, f16* __restrict__ gdL) {
  __shared__ f16 lds[12288];
  const int m0 = blockIdx.x * 64, n0 = blockIdx.y * 128;
  const int t = threadIdx.x;
  const int rowS = t >> 2;
  const int ksw = ((t & 3) ^ ((rowS >> 1) & 3)) * 8;
  const f32x4 VZ = {0.f, 0.f, 0.f, 0.f};
  f32x4 accm[2][4], accc[2][4];
#pragma unroll
  for (int i = 0; i < 2; ++i)
#pragma unroll
    for (int j = 0; j < 4; ++j) { accm[i][j] = VZ; accc[i][j] = VZ; }
  gemm_tile<true>(aoH + (size_t)(m0 + rowS) * CD + ksw,
                  aoL + (size_t)(m0 + rowS) * CD + ksw,
                  gwH + (size_t)(n0 + rowS) * CD + ksw,
                  gwL + (size_t)(n0 + rowS) * CD + ksw,
                  (size_t)64 * CD, CD, lds, accm, accc);
  const int lane = t & 63, wave = t >> 6;
  const int wm = wave >> 1, wn = wave & 1;
  const int m16 = lane & 15, quad = lane >> 4;
#pragma unroll
  for (int sm = 0; sm < 2; ++sm)
#pragma unroll
    for (int sn = 0; sn < 4; ++sn)
#pragma unroll
      for (int r = 0; r < 4; ++r) {
        const int row = m0 + wm * 32 + sm * 16 + quad * 4 + r;
        const int col = n0 + wn * 64 + sn * 16 + m16;
        const float pre = accm[sm][sn][r] + accc[sm][sn][r] * LO_INV + gate_b[col];
        const float g = 1.f / (1.f + __expf(-pre));
        const size_t idx = (size_t)row * CD + col;
        const float ov = (float)aoH[idx] + (float)aoL[idx] * LO_INV;
        f16 hi, lo; fsplit(ov * g, hi, lo);
        gdH[idx] = hi; gdL[idx] = lo;
      }
}

__global__ __launch_bounds__(256) void g_outp(
    const f16* __restrict__ gdH, const f16* __restrict__ gdL,
    const f16* __restrict__ owH, const f16* __restrict__ owL,
    const float* __restrict__ src, float* __restrict__ y1) {
  __shared__ f16 lds[12288];
  const int m0 = blockIdx.x * 64, n0 = blockIdx.y * 128;
  const int t = threadIdx.x;
  const int rowS = t >> 2;
  const int ksw = ((t & 3) ^ ((rowS >> 1) & 3)) * 8;
  const f32x4 VZ = {0.f, 0.f, 0.f, 0.f};
  f32x4 accm[2][4], accc[2][4];
#pragma unroll
  for (int i = 0; i < 2; ++i)
#pragma unroll
    for (int j = 0; j < 4; ++j) { accm[i][j] = VZ; accc[i][j] = VZ; }
  gemm_tile<true>(gdH + (size_t)(m0 + rowS) * CD + ksw,
                  gdL + (size_t)(m0 + rowS) * CD + ksw,
                  owH + (size_t)(n0 + rowS) * CD + ksw,
                  owL + (size_t)(n0 + rowS) * CD + ksw,
                  (size_t)64 * CD, CD, lds, accm, accc);
  const int lane = t & 63, wave = t >> 6;
  const int wm = wave >> 1, wn = wave & 1;
  const int m16 = lane & 15, quad = lane >> 4;
#pragma unroll
  for (int sm = 0; sm < 2; ++sm)
#pragma unroll
    for (int sn = 0; sn < 4; ++sn)
#pragma unroll
      for (int r = 0; r < 4; ++r) {
        const int row = m0 + wm * 32 + sm * 16 + quad * 4 + r;
        const int col = n0 + wn * 64 + sn * 16 + m16;
        const size_t idx = (size_t)row * CD + col;
        y1[idx] = src[idx] + accm[sm][sn][r] + accc[sm][sn][r] * LO_INV;
      }
}

// -------------------------------------------------------------- layernorms

__device__ __forceinline__ void block_reduce2(float &s, float &ss, float* red) {
#pragma unroll
  for (int msk = 32; msk >= 1; msk >>= 1) {
    s += __shfl_xor(s, msk);
    ss += __shfl_xor(ss, msk);
  }
  const int wave = threadIdx.x >> 6, lane = threadIdx.x & 63;
  if (lane == 0) { red[wave] = s; red[4 + wave] = ss; }
  __syncthreads();
  s = red[0] + red[1] + red[2] + red[3];
  ss = red[4] + red[5] + red[6] + red[7];
}

__global__ __launch_bounds__(256) void k_ln1(
    const float* __restrict__ y1, const float* __restrict__ g, const float* __restrict__ bb,
    float* __restrict__ x, f16* __restrict__ xH) {
  __shared__ float red[8];
  const int n = blockIdx.x;
  const float* row = y1 + (size_t)n * CD;
  const int t = threadIdx.x;
  float4 v = *(const float4*)(row + t * 4);
  float a[4] = {v.x, v.y, v.z, v.w};
  float s = a[0] + a[1] + a[2] + a[3];
  float ss = a[0]*a[0] + a[1]*a[1] + a[2]*a[2] + a[3]*a[3];
  block_reduce2(s, ss, red);
  const float mean = s * (1.f / CD);
  const float var = ss * (1.f / CD) - mean * mean;
  const float rstd = rsqrtf(var + 1e-5f);
#pragma unroll
  for (int j = 0; j < 4; ++j) {
    const int d = t * 4 + j;
    const float val = (a[j] - mean) * rstd * g[d] + bb[d];
    x[(size_t)n * CD + d] = val;
    xH[(size_t)n * CD + d] = (f16)val;
  }
}

__global__ __launch_bounds__(256) void k_ln2(
    const float* __restrict__ z, const float* __restrict__ g, const float* __restrict__ bb,
    float* __restrict__ outp) {
  __shared__ float red[8];
  const int n = blockIdx.x;
  const float* row = z + (size_t)n * CD;
  const int t = threadIdx.x;
  float4 v = *(const float4*)(row + t * 4);
  float a[4] = {v.x, v.y, v.z, v.w};
  float s = a[0] + a[1] + a[2] + a[3];
  float ss = a[0]*a[0] + a[1]*a[1] + a[2]*a[2] + a[3]*a[3];
  block_reduce2(s, ss, red);
  const float mean = s * (1.f / CD);
  const float var = ss * (1.f / CD) - mean * mean;
  const float rstd = rsqrtf(var + 1e-5f);
#pragma unroll
  for (int j = 0; j < 4; ++j) {
    const int d = t * 4 + j;
    outp[(size_t)n * CD + d] = (a[j] - mean) * rstd * g[d] + bb[d];
  }
}

// ------------------------------------------------------------------ routing

__global__ void k_zero_counts(int* counts) {
  if (threadIdx.x < CE) counts[threadIdx.x] = 0;
}

__global__ __launch_bounds__(256) void k_route(
    const float* __restrict__ x, const float* __restrict__ gw, const float* __restrict__ gb,
    int* __restrict__ chosen, int* __restrict__ counts, int* __restrict__ bucket) {
  const int wave = threadIdx.x >> 6, lane = threadIdx.x & 63;
  const int n = blockIdx.x * 4 + wave;
  const float* xr = x + (size_t)n * CD;
  float acc[CE];
#pragma unroll
  for (int e = 0; e < CE; ++e) acc[e] = 0.f;
  for (int j = 0; j < 16; ++j) {
    const int d = lane * 16 + j;
    const float xv = xr[d];
    const float* wr = gw + (size_t)d * CE;
#pragma unroll
    for (int e = 0; e < CE; ++e) acc[e] += xv * wr[e];
  }
#pragma unroll
  for (int msk = 32; msk >= 1; msk >>= 1) {
#pragma unroll
    for (int e = 0; e < CE; ++e) acc[e] += __shfl_xor(acc[e], msk);
  }
  if (lane == 0) {
    float best = -1e30f, second = -1e30f;
    int bi = 0, si = 0;
#pragma unroll
    for (int e = 0; e < CE; ++e) {
      const float L = acc[e] + gb[e];
      if (L > best) { second = best; si = bi; best = L; bi = e; }
      else if (L > second) { second = L; si = e; }
    }
    const int ch = bi > si ? bi : si;  // torch-loop semantics: max index wins
    chosen[n] = ch;
    const int pos = atomicAdd(&counts[ch], 1);
    bucket[ch * CN + pos] = n;
  }
}

// ------------------------------------------------------------------ MoE FFN

__global__ __launch_bounds__(256) void g_moe1(
    const f16* __restrict__ xH, const f16* __restrict__ w1t,
    const float* __restrict__ b1, const int* __restrict__ counts,
    const int* __restrict__ bucket, float* __restrict__ hb) {
  const int e = blockIdx.z;
  const int cnt = counts[e];
  const int m0 = blockIdx.x * 64;
  if (m0 >= cnt) return;
  __shared__ f16 lds[6144];
  const int t = threadIdx.x;
  const int rowS = t >> 2;
  const int ksw = ((t & 3) ^ ((rowS >> 1) & 3)) * 8;
  int ra = m0 + rowS; if (ra > cnt - 1) ra = cnt - 1;
  const int tokA = bucket[e * CN + ra];
  const int n0 = blockIdx.y * 128;
  const f32x4 VZ = {0.f, 0.f, 0.f, 0.f};
  f32x4 accm[2][4];
#pragma unroll
  for (int i = 0; i < 2; ++i)
#pragma unroll
    for (int j = 0; j < 4; ++j) accm[i][j] = VZ;
  gemm_tile<false>(xH + (size_t)tokA * CD + ksw, nullptr,
                   w1t + ((size_t)e * CF + n0 + rowS) * CD + ksw, nullptr,
                   (size_t)64 * CD, CD, lds, accm, accm);
  const int lane = t & 63, wave = t >> 6;
  const int wm = wave >> 1, wn = wave & 1;
  const int m16 = lane & 15, quad = lane >> 4;
#pragma unroll
  for (int sm = 0; sm < 2; ++sm)
#pragma unroll
    for (int sn = 0; sn < 4; ++sn)
#pragma unroll
      for (int r = 0; r < 4; ++r) {
        const int rr = m0 + wm * 32 + sm * 16 + quad * 4 + r;
        if (rr >= cnt) continue;
        const int tok = bucket[e * CN + rr];
        const int col = n0 + wn * 64 + sn * 16 + m16;
        hb[(size_t)tok * CF + col] = accm[sm][sn][r] + b1[e * CF + col];
      }
}

__global__ __launch_bounds__(256) void k_lngelu(
    const float* __restrict__ hb, const int* __restrict__ chosen,
    const float* __restrict__ ln_g, const float* __restrict__ ln_b,
    f16* __restrict__ h2) {
  __shared__ float red[8];
  const int n = blockIdx.x;
  const int e = chosen[n];
  const float* row = hb + (size_t)n * CF;
  const int t = threadIdx.x;
  float4 v0 = *(const float4*)(row + t * 8);
  float4 v1 = *(const float4*)(row + t * 8 + 4);
  float a[8] = {v0.x, v0.y, v0.z, v0.w, v1.x, v1.y, v1.z, v1.w};
  float s = 0.f, ss = 0.f;
#pragma unroll
  for (int j = 0; j < 8; ++j) { s += a[j]; ss += a[j] * a[j]; }
  block_reduce2(s, ss, red);
  const float mean = s * (1.f / CF);
  const float var = ss * (1.f / CF) - mean * mean;
  const float rstd = rsqrtf(var + 1e-5f);
  const float* g = ln_g + (size_t)e * CF;
  const float* bb = ln_b + (size_t)e * CF;
#pragma unroll
  for (int j = 0; j < 8; ++j) {
    const int d = t * 8 + j;
    const float val = (a[j] - mean) * rstd * g[d] + bb[d];
    const float gl = 0.5f * val * (1.f + erff(val * 0.70710678118654752f));
    h2[(size_t)n * CF + d] = (f16)gl;
  }
}

__global__ __launch_bounds__(256) void g_moe2(
    const f16* __restrict__ h2, const f16* __restrict__ w2t,
    const float* __restrict__ b2, const float* __restrict__ rsc,
    const int* __restrict__ counts, const int* __restrict__ bucket,
    const float* __restrict__ x, float* __restrict__ z) {
  const int e = blockIdx.z;
  const int cnt = counts[e];
  const int m0 = blockIdx.x * 64;
  if (m0 >= cnt) return;
  __shared__ f16 lds[6144];
  const int t = threadIdx.x;
  const int rowS = t >> 2;
  const int ksw = ((t & 3) ^ ((rowS >> 1) & 3)) * 8;
  int ra = m0 + rowS; if (ra > cnt - 1) ra = cnt - 1;
  const int tokA = bucket[e * CN + ra];
  const int n0 = blockIdx.y * 128;
  const f32x4 VZ = {0.f, 0.f, 0.f, 0.f};
  f32x4 accm[2][4];
#pragma unroll
  for (int i = 0; i < 2; ++i)
#pragma unroll
    for (int j = 0; j < 4; ++j) accm[i][j] = VZ;
  gemm_tile<false>(h2 + (size_t)tokA * CF + ksw, nullptr,
                   w2t + ((size_t)e * CD + n0 + rowS) * CF + ksw, nullptr,
                   (size_t)64 * CF, CF, lds, accm, accm);
  const float rs = rsc[e];
  const int lane = t & 63, wave = t >> 6;
  const int wm = wave >> 1, wn = wave & 1;
  const int m16 = lane & 15, quad = lane >> 4;
#pragma unroll
  for (int sm = 0; sm < 2; ++sm)
#pragma unroll
    for (int sn = 0; sn < 4; ++sn)
#pragma unroll
      for (int r = 0; r < 4; ++r) {
        const int rr = m0 + wm * 32 + sm * 16 + quad * 4 + r;
        if (rr >= cnt) continue;
        const int tok = bucket[e * CN + rr];
        const int col = n0 + wn * 64 + sn * 16 + m16;
        const size_t idx = (size_t)tok * CD + col;
        // z = x + moe ; moe = (h2@W2 + b2)*rsc + x   (top-2 weight sum == 1)
        z[idx] = 2.f * x[idx] + (accm[sm][sn][r] + b2[e * CD + col]) * rs;
      }
}

// ------------------------------------------------------------------- launch

extern "C" void kernel_launch(void* const* d_in, const int* in_sizes, int n_in,
                              void* d_out, int out_size, void* d_ws, size_t ws_size,
                              hipStream_t stream) {
  (void)in_sizes; (void)n_in; (void)out_size; (void)ws_size;
  const float* src        = (const float*)d_in[0];
  const float* q_w        = (const float*)d_in[1];
  const float* k_w        = (const float*)d_in[2];
  const float* v_w        = (const float*)d_in[3];
  const float* out_w      = (const float*)d_in[4];
  const float* gate_w     = (const float*)d_in[5];
  const float* gate_b     = (const float*)d_in[6];
  const float* scale_w    = (const float*)d_in[7];
  const float* n1_g       = (const float*)d_in[8];
  const float* n1_b       = (const float*)d_in[9];
  const float* n2_g       = (const float*)d_in[10];
  const float* n2_b       = (const float*)d_in[11];
  const float* moe_gate_w = (const float*)d_in[12];
  const float* moe_gate_b = (const float*)d_in[13];
  const float* w1         = (const float*)d_in[14];
  const float* b1         = (const float*)d_in[15];
  const float* ln_g       = (const float*)d_in[16];
  const float* ln_b       = (const float*)d_in[17];
  const float* w2         = (const float*)d_in[18];
  const float* b2         = (const float*)d_in[19];
  const float* res_scale  = (const float*)d_in[20];
  float* outp = (float*)d_out;

  char* p = (char*)d_ws;
  auto take = [&](size_t bytes) -> char* {
    char* r = p;
    p += (bytes + 255) & ~(size_t)255;
    return r;
  };
  f16* srcH = (f16*)take((size_t)CN * CD * 2);
  f16* srcL = (f16*)take((size_t)CN * CD * 2);
  f16* qwH = (f16*)take((size_t)CD * CD * 2);
  f16* qwL = (f16*)take((size_t)CD * CD * 2);
  f16* kwH = (f16*)take((size_t)CD * CD * 2);
  f16* kwL = (f16*)take((size_t)CD * CD * 2);
  f16* vwH = (f16*)take((size_t)CD * CD * 2);
  f16* vwL = (f16*)take((size_t)CD * CD * 2);
  f16* gwH = (f16*)take((size_t)CD * CD * 2);
  f16* gwL = (f16*)take((size_t)CD * CD * 2);
  f16* owH = (f16*)take((size_t)CD * CD * 2);
  f16* owL = (f16*)take((size_t)CD * CD * 2);
  f16* qH = (f16*)take((size_t)CBH * CS * CHD * 2);
  f16* qL = (f16*)take((size_t)CBH * CS * CHD * 2);
  f16* kH = (f16*)take((size_t)CBH * CS * CHD * 2);
  f16* kL = (f16*)take((size_t)CBH * CS * CHD * 2);
  f16* vTH = (f16*)take((size_t)CBH * CS * CHD * 2);
  f16* vTL = (f16*)take((size_t)CBH * CS * CHD * 2);
  f16* aoH = (f16*)take((size_t)CN * CD * 2);
  f16* aoL = (f16*)take((size_t)CN * CD * 2);
  f16* gdH = (f16*)take((size_t)CN * CD * 2);
  f16* gdL = (f16*)take((size_t)CN * CD * 2);
  float* y1 = (float*)take((size_t)CN * CD * 4);
  float* x  = (float*)take((size_t)CN * CD * 4);
  f16* xH = (f16*)take((size_t)CN * CD * 2);
  int* counts = (int*)take(64);
  int* bucket = (int*)take((size_t)CE * CN * 4);
  int* chosen = (int*)take((size_t)CN * 4);
  float* hb = (float*)take((size_t)CN * CF * 4);
  f16* h2 = (f16*)take((size_t)CN * CF * 2);
  f16* w1t = (f16*)take((size_t)CE * CF * CD * 2);
  f16* w2t = (f16*)take((size_t)CE * CD * CF * 2);
  float* zb = (float*)take((size_t)CN * CD * 4);

  // --- input conversion / weight transposition ---
  k_split_cvt<<<dim3(CN * CD / 4 / 256), 256, 0, stream>>>(src, srcH, srcL, CN * CD);
  dim3 tb(32, 8);
  k_transpose_split<<<dim3(CD / 32, CD / 32, 1), tb, 0, stream>>>(q_w, qwH, qwL, CD, CD);
  k_transpose_split<<<dim3(CD / 32, CD / 32, 1), tb, 0, stream>>>(k_w, kwH, kwL, CD, CD);
  k_transpose_split<<<dim3(CD / 32, CD / 32, 1), tb, 0, stream>>>(v_w, vwH, vwL, CD, CD);
  k_transpose_split<<<dim3(CD / 32, CD / 32, 1), tb, 0, stream>>>(gate_w, gwH, gwL, CD, CD);
  k_transpose_split<<<dim3(CD / 32, CD / 32, 1), tb, 0, stream>>>(out_w, owH, owL, CD, CD);
  k_transpose_split<<<dim3(CF / 32, CD / 32, CE), tb, 0, stream>>>(w1, w1t, nullptr, CD, CF);
  k_transpose_split<<<dim3(CD / 32, CF / 32, CE), tb, 0, stream>>>(w2, w2t, nullptr, CF, CD);

  // --- attention ---
  g_qkv<<<dim3(CN / 64, CD / 128, 3), 256, 0, stream>>>(
      srcH, srcL, qwH, qwL, kwH, kwL, vwH, vwL, qH, qL, kH, kL, vTH, vTL);
  k_fattn<<<dim3(CS / 64, CBH), 256, 0, stream>>>(
      qH, qL, kH, kL, vTH, vTL, scale_w, aoH, aoL);
  g_gate<<<dim3(CN / 64, CD / 128), 256, 0, stream>>>(aoH, aoL, gwH, gwL, gate_b, gdH, gdL);
  g_outp<<<dim3(CN / 64, CD / 128), 256, 0, stream>>>(gdH, gdL, owH, owL, src, y1);
  k_ln1<<<dim3(CN), 256, 0, stream>>>(y1, n1_g, n1_b, x, xH);

  // --- routing + MoE ---
  k_zero_counts<<<dim3(1), 64, 0, stream>>>(counts);
  k_route<<<dim3(CN / 4), 256, 0, stream>>>(x, moe_gate_w, moe_gate_b, chosen, counts, bucket);
  g_moe1<<<dim3(CN / 64, CF / 128, CE), 256, 0, stream>>>(xH, w1t, b1, counts, bucket, hb);
  k_lngelu<<<dim3(CN), 256, 0, stream>>>(hb, chosen, ln_g, ln_b, h2);
  g_moe2<<<dim3(CN / 64, CD / 128, CE), 256, 0, stream>>>(h2, w2t, b2, res_scale, counts, bucket, x, zb);
  k_ln2<<<dim3(CN), 256, 0, stream>>>(zb, n2_g, n2_b, outp);
}